// Round 1
// baseline (8471.382 us; speedup 1.0000x reference)
//
#include <hip/hip_runtime.h>
#include <hip/hip_cooperative_groups.h>

namespace cg = cooperative_groups;

typedef _Float16 f16;
typedef _Float16 h8 __attribute__((ext_vector_type(8)));
typedef float f4 __attribute__((ext_vector_type(4)));

#define Bn 32
#define Tn 256
#define Sn 256
#define Hn 1024
#define INn 2560          // 3*D + H
#define KT 3584           // INn + Hn (combined gates K)

__device__ __forceinline__ f4 mfma_f16(h8 a, h8 b, f4 c) {
  return __builtin_amdgcn_mfma_f32_16x16x32_f16(a, b, c, 0, 0, 0);
}
__device__ __forceinline__ float sigm(float x) { return 1.0f / (1.0f + __expf(-x)); }

// ---------------------------------------------------------------------------
// prep kernels (one-time per launch)
// ---------------------------------------------------------------------------
__global__ void k_prep_weights(const float* __restrict__ W_ih, const float* __restrict__ W_hh,
                               const float* __restrict__ Wa_in, const float* __restrict__ Wc_in,
                               const float* __restrict__ Wa_out, const float* __restrict__ b_ih,
                               const float* __restrict__ b_hh,
                               f16* __restrict__ Wcomb, f16* __restrict__ Wain,
                               f16* __restrict__ Wcin, f16* __restrict__ Waout,
                               float* __restrict__ bcomb) {
  long idx = (long)blockIdx.x * 256 + threadIdx.x;
  if (idx < 14680064L) {  // Wcomb[4096][3584] = [W_ih | W_hh] rows
    int n = (int)(idx / KT), k = (int)(idx % KT);
    float v = (k < INn) ? W_ih[(long)n * INn + k] : W_hh[(long)n * Hn + (k - INn)];
    Wcomb[idx] = (f16)v;
    return;
  }
  idx -= 14680064L;
  if (idx < 1048576) { Wain[idx] = (f16)Wa_in[idx]; return; }
  idx -= 1048576;
  if (idx < 1048576) { Wcin[idx] = (f16)Wc_in[idx]; return; }
  idx -= 1048576;
  if (idx < 2097152) { Waout[idx] = (f16)Wa_out[idx]; return; }
  idx -= 2097152;
  if (idx < 4096) bcomb[idx] = b_ih[idx] + b_hh[idx];
}

__global__ void k_prep_ctx(const float* __restrict__ context,
                           f16* __restrict__ ctx16, f16* __restrict__ ctxT) {
  int idx = blockIdx.x * 256 + threadIdx.x;       // 32*256*1024 = 8388608
  int b = idx >> 18;
  int rem = idx & 262143;
  int s = rem >> 10, k = rem & 1023;
  float v = context[idx];
  ctx16[idx] = (f16)v;
  ctxT[((long)b << 18) + ((long)k << 8) + s] = (f16)v;  // [b][k][s]
}

__global__ void k_prep_xemb(const int* __restrict__ nt, const int* __restrict__ prev_r,
                            const int* __restrict__ par_r,
                            const float* __restrict__ nt_emb, const float* __restrict__ rule_emb,
                            f16* __restrict__ xemb) {
  int bt = blockIdx.x;                 // b*256 + t
  int nti = nt[bt], pri = prev_r[bt], pai = par_r[bt];
  f16* dst = xemb + (long)bt * 1536;
  for (int k = threadIdx.x; k < 1536; k += 256) {
    float v;
    if (k < 512)       v = nt_emb[(long)nti * 512 + k];
    else if (k < 1024) v = rule_emb[(long)pri * 512 + (k - 512)];
    else               v = rule_emb[(long)pai * 512 + (k - 1024)];
    dst[k] = (f16)v;
  }
}

__global__ void k_prep_state(const float* __restrict__ c0, float* __restrict__ cbuf,
                             f16* __restrict__ bufh) {
  int idx = blockIdx.x * 256 + threadIdx.x;   // 32768
  cbuf[idx] = c0[idx];
  int b = idx >> 10, k = idx & 1023;
  bufh[(long)b * 257 * Hn + k] = (f16)0.f;    // buf slot 0 = zeros (parent fallback; == h0)
}

// ---------------------------------------------------------------------------
// Phase 1: sequential LSTM recurrence. 64 blocks x 512 threads (cooperative).
// Block jt owns h-columns [jt*16, jt*16+16) for all 4 gates; the 8 waves split
// K=3584 into 8 chunks of 448; cell epilogue fused (no extra sync).
// ---------------------------------------------------------------------------
struct GatesArgs {
  const f16* xemb; const f16* Wcomb; f16* bufh; float* cbuf;
  const float* bcomb; const int* parent_t;
};

__global__ void __launch_bounds__(512, 1) k_gates(GatesArgs a) {
  cg::grid_group grid = cg::this_grid();
  const int jt = blockIdx.x;
  const int tid = threadIdx.x;
  const int wave = tid >> 6;            // kq chunk 0..7
  const int lane = tid & 63;
  const int l15 = lane & 15, quad = lane >> 4;

  __shared__ float sC[4][4][32][16];    // 32 KB partial C
  __shared__ int spidx[32];

  const f16* wrow[4];
#pragma unroll
  for (int g = 0; g < 4; ++g)
    wrow[g] = a.Wcomb + (long)(g * Hn + jt * 16 + l15) * KT;

  for (int t = 0; t < Tn; ++t) {
    if (tid < 32) {
      int pt = a.parent_t[tid * Tn + t];
      spidx[tid] = (pt < t) ? pt + 1 : 0;
    }
    __syncthreads();
    int pidx0 = spidx[l15];
    int pidx1 = spidx[16 + l15];

    f4 acc[2][4];
#pragma unroll
    for (int i = 0; i < 2; ++i)
#pragma unroll
      for (int g = 0; g < 4; ++g) acc[i][g] = (f4){0.f, 0.f, 0.f, 0.f};

    for (int ks = 0; ks < 14; ++ks) {
      int k = wave * 448 + ks * 32 + quad * 8;
      h8 a0, a1;
      if (k < 1536) {                 // embeddings
        a0 = *(const h8*)(a.xemb + ((long)(l15 * Tn + t) * 1536 + k));
        a1 = *(const h8*)(a.xemb + ((long)((16 + l15) * Tn + t) * 1536 + k));
      } else if (k < INn) {           // parent state
        a0 = *(const h8*)(a.bufh + ((long)(l15 * 257 + pidx0) * Hn + (k - 1536)));
        a1 = *(const h8*)(a.bufh + ((long)((16 + l15) * 257 + pidx1) * Hn + (k - 1536)));
      } else {                        // h_prev (t=0 -> slot 0 == zeros == h0)
        a0 = *(const h8*)(a.bufh + ((long)(l15 * 257 + t) * Hn + (k - INn)));
        a1 = *(const h8*)(a.bufh + ((long)((16 + l15) * 257 + t) * Hn + (k - INn)));
      }
#pragma unroll
      for (int g = 0; g < 4; ++g) {
        h8 bf = *(const h8*)(wrow[g] + k);
        acc[0][g] = mfma_f16(a0, bf, acc[0][g]);
        acc[1][g] = mfma_f16(a1, bf, acc[1][g]);
      }
    }

    // two-stage partial reduction into 32KB LDS (C layout: col=lane&15, row=quad*4+r)
    if (wave < 4) {
#pragma unroll
      for (int g = 0; g < 4; ++g)
#pragma unroll
        for (int r = 0; r < 4; ++r) {
          sC[wave][g][quad * 4 + r][l15]      = acc[0][g][r];
          sC[wave][g][16 + quad * 4 + r][l15] = acc[1][g][r];
        }
    }
    __syncthreads();
    if (wave >= 4) {
      int w = wave - 4;
#pragma unroll
      for (int g = 0; g < 4; ++g)
#pragma unroll
        for (int r = 0; r < 4; ++r) {
          sC[w][g][quad * 4 + r][l15]      += acc[0][g][r];
          sC[w][g][16 + quad * 4 + r][l15] += acc[1][g][r];
        }
    }
    __syncthreads();

    // fused LSTM cell: 512 threads = 32 batches x 16 cols
    {
      int b = tid >> 4, jj = tid & 15;
      int j = jt * 16 + jj;
      float g0 = 0.f, g1 = 0.f, g2 = 0.f, g3 = 0.f;
#pragma unroll
      for (int w = 0; w < 4; ++w) {
        g0 += sC[w][0][b][jj]; g1 += sC[w][1][b][jj];
        g2 += sC[w][2][b][jj]; g3 += sC[w][3][b][jj];
      }
      g0 += a.bcomb[j];
      g1 += a.bcomb[Hn + j];
      g2 += a.bcomb[2 * Hn + j];
      g3 += a.bcomb[3 * Hn + j];
      float cp = a.cbuf[b * Hn + j];
      float cn = sigm(g1) * cp + sigm(g0) * tanhf(g2);
      float hn = sigm(g3) * tanhf(cn);
      a.cbuf[b * Hn + j] = cn;
      a.bufh[((long)b * 257 + t + 1) * Hn + j] = (f16)hn;
    }
    grid.sync();
  }
}

// ---------------------------------------------------------------------------
// Phase 2: bulk attention GEMMs (fp16 MFMA, 64x64 block tile, 4 waves 2x2)
// ---------------------------------------------------------------------------
// qW/qc: C[8192,1024] = A[8192,1024] @ W[1024,1024]^T ; a_mode=1: A rows from bufh
__global__ void k_qgemm(const f16* __restrict__ A, const f16* __restrict__ W,
                        f16* __restrict__ out, int a_mode) {
  int tid = threadIdx.x, lane = tid & 63, wave = tid >> 6;
  int l15 = lane & 15, quad = lane >> 4;
  int wm = wave & 1, wn = wave >> 1;
  int bm = blockIdx.y * 64 + wm * 32, bn = blockIdx.x * 64 + wn * 32;

  const f16* arow[2]; const f16* brow[2];
#pragma unroll
  for (int i = 0; i < 2; ++i) {
    int m = bm + i * 16 + l15;
    arow[i] = a_mode ? A + ((long)(m >> 8) * 257 + (m & 255) + 1) * Hn
                     : A + (long)m * 1024;
  }
#pragma unroll
  for (int j = 0; j < 2; ++j) brow[j] = W + (long)(bn + j * 16 + l15) * 1024;

  f4 acc[2][2];
#pragma unroll
  for (int i = 0; i < 2; ++i)
#pragma unroll
    for (int j = 0; j < 2; ++j) acc[i][j] = (f4){0.f, 0.f, 0.f, 0.f};

  for (int ks = 0; ks < 32; ++ks) {
    int k = ks * 32 + quad * 8;
    h8 af[2] = {*(const h8*)(arow[0] + k), *(const h8*)(arow[1] + k)};
    h8 bf[2] = {*(const h8*)(brow[0] + k), *(const h8*)(brow[1] + k)};
#pragma unroll
    for (int i = 0; i < 2; ++i)
#pragma unroll
      for (int j = 0; j < 2; ++j) acc[i][j] = mfma_f16(af[i], bf[j], acc[i][j]);
  }
#pragma unroll
  for (int i = 0; i < 2; ++i)
#pragma unroll
    for (int j = 0; j < 2; ++j)
#pragma unroll
      for (int r = 0; r < 4; ++r) {
        int m = bm + i * 16 + quad * 4 + r;
        int n = bn + j * 16 + l15;
        out[(long)m * 1024 + n] = (f16)acc[i][j][r];
      }
}

// scores: per-batch C[256,256] = Q[256,1024] @ ctx[b][256,1024]^T -> raw fp32
__global__ void k_scores(const f16* __restrict__ Q, const f16* __restrict__ C16,
                         float* __restrict__ outp) {
  int tid = threadIdx.x, lane = tid & 63, wave = tid >> 6;
  int l15 = lane & 15, quad = lane >> 4;
  int wm = wave & 1, wn = wave >> 1;
  int b = blockIdx.z;
  int bm = blockIdx.y * 64 + wm * 32, bn = blockIdx.x * 64 + wn * 32;
  const f16* A = Q + (long)b * 256 * 1024;
  const f16* Bp = C16 + (long)b * 256 * 1024;
  const f16* arow[2]; const f16* brow[2];
#pragma unroll
  for (int i = 0; i < 2; ++i) arow[i] = A + (long)(bm + i * 16 + l15) * 1024;
#pragma unroll
  for (int j = 0; j < 2; ++j) brow[j] = Bp + (long)(bn + j * 16 + l15) * 1024;
  f4 acc[2][2];
#pragma unroll
  for (int i = 0; i < 2; ++i)
#pragma unroll
    for (int j = 0; j < 2; ++j) acc[i][j] = (f4){0.f, 0.f, 0.f, 0.f};
  for (int ks = 0; ks < 32; ++ks) {
    int k = ks * 32 + quad * 8;
    h8 af[2] = {*(const h8*)(arow[0] + k), *(const h8*)(arow[1] + k)};
    h8 bf[2] = {*(const h8*)(brow[0] + k), *(const h8*)(brow[1] + k)};
#pragma unroll
    for (int i = 0; i < 2; ++i)
#pragma unroll
      for (int j = 0; j < 2; ++j) acc[i][j] = mfma_f16(af[i], bf[j], acc[i][j]);
  }
#pragma unroll
  for (int i = 0; i < 2; ++i)
#pragma unroll
    for (int j = 0; j < 2; ++j)
#pragma unroll
      for (int r = 0; r < 4; ++r) {
        int m = bm + i * 16 + quad * 4 + r;
        int n = bn + j * 16 + l15;
        outp[((long)b * 256 + m) * 256 + n] = acc[i][j][r];
      }
}

// masked softmax over S=256; in-place fp32; optional fp16 copy for c_vec GEMM
__global__ void k_softmax(float* __restrict__ rows, const int* __restrict__ ctx_len,
                          f16* __restrict__ pout) {
  int tid = threadIdx.x;
  long base = (long)blockIdx.x * 256;
  int b = blockIdx.x >> 8;
  int len = ctx_len[b];
  float v = rows[base + tid];
  bool valid = tid < len;
  __shared__ float red[256];
  red[tid] = valid ? v : -3.0e38f;
  __syncthreads();
  for (int o = 128; o > 0; o >>= 1) {
    if (tid < o) red[tid] = fmaxf(red[tid], red[tid + o]);
    __syncthreads();
  }
  float m = red[0];
  __syncthreads();
  float e = valid ? __expf(v - m) : 0.f;
  red[tid] = e;
  __syncthreads();
  for (int o = 128; o > 0; o >>= 1) {
    if (tid < o) red[tid] += red[tid + o];
    __syncthreads();
  }
  float p = e / red[0];
  rows[base + tid] = p;
  if (pout) pout[base + tid] = (f16)p;
}

// c_vec: per-batch C[256,1024] = P[256,256] @ ctxT[b][1024,256]^T
__global__ void k_cvec(const f16* __restrict__ P, const f16* __restrict__ CT,
                       f16* __restrict__ out) {
  int tid = threadIdx.x, lane = tid & 63, wave = tid >> 6;
  int l15 = lane & 15, quad = lane >> 4;
  int wm = wave & 1, wn = wave >> 1;
  int b = blockIdx.z;
  int bm = blockIdx.y * 64 + wm * 32, bn = blockIdx.x * 64 + wn * 32;
  const f16* A = P + (long)b * 256 * 256;
  const f16* Bp = CT + (long)b * 1024 * 256;
  const f16* arow[2]; const f16* brow[2];
#pragma unroll
  for (int i = 0; i < 2; ++i) arow[i] = A + (long)(bm + i * 16 + l15) * 256;
#pragma unroll
  for (int j = 0; j < 2; ++j) brow[j] = Bp + (long)(bn + j * 16 + l15) * 256;
  f4 acc[2][2];
#pragma unroll
  for (int i = 0; i < 2; ++i)
#pragma unroll
    for (int j = 0; j < 2; ++j) acc[i][j] = (f4){0.f, 0.f, 0.f, 0.f};
  for (int ks = 0; ks < 8; ++ks) {
    int k = ks * 32 + quad * 8;
    h8 af[2] = {*(const h8*)(arow[0] + k), *(const h8*)(arow[1] + k)};
    h8 bf[2] = {*(const h8*)(brow[0] + k), *(const h8*)(brow[1] + k)};
#pragma unroll
    for (int i = 0; i < 2; ++i)
#pragma unroll
      for (int j = 0; j < 2; ++j) acc[i][j] = mfma_f16(af[i], bf[j], acc[i][j]);
  }
#pragma unroll
  for (int i = 0; i < 2; ++i)
#pragma unroll
    for (int j = 0; j < 2; ++j)
#pragma unroll
      for (int r = 0; r < 4; ++r) {
        int m = bm + i * 16 + quad * 4 + r;
        int n = bn + j * 16 + l15;
        out[((long)b * 256 + m) * 1024 + n] = (f16)acc[i][j][r];
      }
}

// a_out: C[8192,1024] = tanh([c_vec | h] @ Wa_out^T); writes fp32 d_out + fp16 copy
__global__ void k_aout(const f16* __restrict__ CV, const f16* __restrict__ bufh,
                       const f16* __restrict__ W, float* __restrict__ outf,
                       f16* __restrict__ outh) {
  int tid = threadIdx.x, lane = tid & 63, wave = tid >> 6;
  int l15 = lane & 15, quad = lane >> 4;
  int wm = wave & 1, wn = wave >> 1;
  int bm = blockIdx.y * 64 + wm * 32, bn = blockIdx.x * 64 + wn * 32;
  const f16* arow1[2]; const f16* arow2[2]; const f16* brow[2];
#pragma unroll
  for (int i = 0; i < 2; ++i) {
    int m = bm + i * 16 + l15;
    arow1[i] = CV + (long)m * 1024;
    arow2[i] = bufh + ((long)(m >> 8) * 257 + (m & 255) + 1) * Hn;
  }
#pragma unroll
  for (int j = 0; j < 2; ++j) brow[j] = W + (long)(bn + j * 16 + l15) * 2048;
  f4 acc[2][2];
#pragma unroll
  for (int i = 0; i < 2; ++i)
#pragma unroll
    for (int j = 0; j < 2; ++j) acc[i][j] = (f4){0.f, 0.f, 0.f, 0.f};
  for (int ks = 0; ks < 64; ++ks) {
    int k = ks * 32 + quad * 8;
    h8 af[2], bf[2];
    if (k < 1024) {
      af[0] = *(const h8*)(arow1[0] + k);
      af[1] = *(const h8*)(arow1[1] + k);
    } else {
      af[0] = *(const h8*)(arow2[0] + (k - 1024));
      af[1] = *(const h8*)(arow2[1] + (k - 1024));
    }
    bf[0] = *(const h8*)(brow[0] + k);
    bf[1] = *(const h8*)(brow[1] + k);
#pragma unroll
    for (int i = 0; i < 2; ++i)
#pragma unroll
      for (int j = 0; j < 2; ++j) acc[i][j] = mfma_f16(af[i], bf[j], acc[i][j]);
  }
#pragma unroll
  for (int i = 0; i < 2; ++i)
#pragma unroll
    for (int j = 0; j < 2; ++j)
#pragma unroll
      for (int r = 0; r < 4; ++r) {
        int m = bm + i * 16 + quad * 4 + r;
        int n = bn + j * 16 + l15;
        float v = tanhf(acc[i][j][r]);
        outf[(long)m * 1024 + n] = v;
        outh[(long)m * 1024 + n] = (f16)v;
      }
}

// ---------------------------------------------------------------------------
extern "C" void kernel_launch(void* const* d_in, const int* in_sizes, int n_in,
                              void* d_out, int out_size, void* d_ws, size_t ws_size,
                              hipStream_t stream) {
  const int*   nt        = (const int*)d_in[0];
  const int*   prev_r    = (const int*)d_in[1];
  const int*   par_r     = (const int*)d_in[2];
  const int*   parent_t  = (const int*)d_in[3];
  const float* context   = (const float*)d_in[4];
  const int*   ctx_len   = (const int*)d_in[5];
  const float* c0        = (const float*)d_in[7];   // h0 (d_in[6]) is zeros == buf slot 0
  const float* nt_emb    = (const float*)d_in[8];
  const float* rule_emb  = (const float*)d_in[9];
  const float* W_ih      = (const float*)d_in[10];
  const float* W_hh      = (const float*)d_in[11];
  const float* b_ih      = (const float*)d_in[12];
  const float* b_hh      = (const float*)d_in[13];
  const float* Wa_in     = (const float*)d_in[14];
  const float* Wa_out    = (const float*)d_in[15];
  const float* Wc_in     = (const float*)d_in[16];
  // d_in[17] (Wc_out) unused: reference discards copy-attention's output proj.
  float* out = (float*)d_out;

  char* ws = (char*)d_ws;
  f16*   bufh  = (f16*)(ws);                       // [32][257][1024]   16,842,752 B
  f16*   xemb  = (f16*)(ws + 16842752L);           // [32][256][1536]   25,165,824
  f16*   Wcomb = (f16*)(ws + 42008576L);           // [4096][3584]      29,360,128
  f16*   Wain  = (f16*)(ws + 71368704L);           // [1024][1024]       2,097,152
  f16*   Wcin  = (f16*)(ws + 73465856L);           // [1024][1024]       2,097,152
  f16*   Waout = (f16*)(ws + 75563008L);           // [1024][2048]       4,194,304
  f16*   ctx16 = (f16*)(ws + 79757312L);           // [32][256][1024]   16,777,216
  f16*   ctxT  = (f16*)(ws + 96534528L);           // [32][1024][256]   16,777,216
  f16*   qbuf  = (f16*)(ws + 113311744L);          // [8192][1024]      16,777,216
  f16*   pbuf  = (f16*)(ws + 130088960L);          // [8192][256]        4,194,304
  f16*   cvec  = (f16*)(ws + 134283264L);          // [8192][1024]      16,777,216
  f16*   aout16= (f16*)(ws + 151060480L);          // [8192][1024]      16,777,216
  float* cbuf  = (float*)(ws + 167837696L);        // [32][1024] fp32      131,072
  float* bcomb = (float*)(ws + 167968768L);        // [4096] fp32           16,384

  float* attn_out = out + 8388608;   // [B,T,S]
  float* copy_out = out + 10485760;  // [B,T,S]

  // -------- prep --------
  hipLaunchKernelGGL(k_prep_weights, dim3(73744), dim3(256), 0, stream,
                     W_ih, W_hh, Wa_in, Wc_in, Wa_out, b_ih, b_hh,
                     Wcomb, Wain, Wcin, Waout, bcomb);
  hipLaunchKernelGGL(k_prep_ctx, dim3(32768), dim3(256), 0, stream, context, ctx16, ctxT);
  hipLaunchKernelGGL(k_prep_xemb, dim3(8192), dim3(256), 0, stream,
                     nt, prev_r, par_r, nt_emb, rule_emb, xemb);
  hipLaunchKernelGGL(k_prep_state, dim3(128), dim3(256), 0, stream, c0, cbuf, bufh);

  // -------- phase 1: sequential recurrence (cooperative, 256 grid syncs) --------
  GatesArgs ga{xemb, Wcomb, bufh, cbuf, bcomb, parent_t};
  void* gp[] = {&ga};
  hipLaunchCooperativeKernel((void*)k_gates, dim3(64), dim3(512), gp, 0, stream);

  // -------- phase 2: bulk attention over all (b,t) --------
  hipLaunchKernelGGL(k_qgemm, dim3(16, 128), dim3(256), 0, stream, bufh, Wain, qbuf, 1);
  hipLaunchKernelGGL(k_scores, dim3(4, 4, 32), dim3(256), 0, stream, qbuf, ctx16, attn_out);
  hipLaunchKernelGGL(k_softmax, dim3(8192), dim3(256), 0, stream, attn_out, ctx_len, pbuf);
  hipLaunchKernelGGL(k_cvec, dim3(16, 4, 32), dim3(256), 0, stream, pbuf, ctxT, cvec);
  hipLaunchKernelGGL(k_aout, dim3(16, 128), dim3(256), 0, stream, cvec, bufh, Waout, out, aout16);
  hipLaunchKernelGGL(k_qgemm, dim3(16, 128), dim3(256), 0, stream, aout16, Wcin, qbuf, 0);
  hipLaunchKernelGGL(k_scores, dim3(4, 4, 32), dim3(256), 0, stream, qbuf, ctx16, copy_out);
  hipLaunchKernelGGL(k_softmax, dim3(8192), dim3(256), 0, stream, copy_out, ctx_len, (f16*)nullptr);
}

// Round 2
// 4134.584 us; speedup vs baseline: 2.0489x; 2.0489x over previous
//
#include <hip/hip_runtime.h>

typedef _Float16 f16;
typedef _Float16 h8 __attribute__((ext_vector_type(8)));
typedef float f4 __attribute__((ext_vector_type(4)));

#define Bn 32
#define Tn 256
#define Sn 256
#define Hn 1024
#define INn 2560          // 3*D + H
#define KT 3584           // INn + Hn (combined gates K)
#define SW_PAD 3592       // 3584 + 8 f16 pad: breaks LDS bank aliasing for ds_read_b128

__device__ __forceinline__ f4 mfma_f16(h8 a, h8 b, f4 c) {
  return __builtin_amdgcn_mfma_f32_16x16x32_f16(a, b, c, 0, 0, 0);
}
__device__ __forceinline__ float sigm(float x) { return 1.0f / (1.0f + __expf(-x)); }

// system-scope (sc0 sc1) 16B load: bypasses L2 -> reads MALL directly.
// Relaxed atomics: no fences, compiler tracks vmcnt deps and can pipeline.
__device__ __forceinline__ h8 ld_sys16(const f16* p) {
  unsigned long long lo = __hip_atomic_load((const unsigned long long*)p,
                                            __ATOMIC_RELAXED, __HIP_MEMORY_SCOPE_SYSTEM);
  unsigned long long hi = __hip_atomic_load(((const unsigned long long*)p) + 1,
                                            __ATOMIC_RELAXED, __HIP_MEMORY_SCOPE_SYSTEM);
  struct U { unsigned long long a, b; } u{lo, hi};
  return __builtin_bit_cast(h8, u);
}

// ---------------------------------------------------------------------------
// prep kernels
// ---------------------------------------------------------------------------
__global__ void k_prep_weights(const float* __restrict__ W_ih, const float* __restrict__ W_hh,
                               const float* __restrict__ Wa_in, const float* __restrict__ Wc_in,
                               const float* __restrict__ Wa_out, const float* __restrict__ b_ih,
                               const float* __restrict__ b_hh,
                               f16* __restrict__ Wcomb, f16* __restrict__ Wain,
                               f16* __restrict__ Wcin, f16* __restrict__ Waout,
                               float* __restrict__ bcomb) {
  long idx = (long)blockIdx.x * 256 + threadIdx.x;
  if (idx < 14680064L) {  // Wcomb[4096][3584] = [W_ih | W_hh] rows
    int n = (int)(idx / KT), k = (int)(idx % KT);
    float v = (k < INn) ? W_ih[(long)n * INn + k] : W_hh[(long)n * Hn + (k - INn)];
    Wcomb[idx] = (f16)v;
    return;
  }
  idx -= 14680064L;
  if (idx < 1048576) { Wain[idx] = (f16)Wa_in[idx]; return; }
  idx -= 1048576;
  if (idx < 1048576) { Wcin[idx] = (f16)Wc_in[idx]; return; }
  idx -= 1048576;
  if (idx < 2097152) { Waout[idx] = (f16)Wa_out[idx]; return; }
  idx -= 2097152;
  if (idx < 4096) bcomb[idx] = b_ih[idx] + b_hh[idx];
}

__global__ void k_prep_ctx(const float* __restrict__ context,
                           f16* __restrict__ ctx16, f16* __restrict__ ctxT) {
  int idx = blockIdx.x * 256 + threadIdx.x;       // 8388608
  int b = idx >> 18;
  int rem = idx & 262143;
  int s = rem >> 10, k = rem & 1023;
  float v = context[idx];
  ctx16[idx] = (f16)v;
  ctxT[((long)b << 18) + ((long)k << 8) + s] = (f16)v;  // [b][k][s]
}

// xemb layout [t][b][1536]: per-step slice is one contiguous 96 KB blob (L2-friendly)
__global__ void k_prep_xemb(const int* __restrict__ nt, const int* __restrict__ prev_r,
                            const int* __restrict__ par_r,
                            const float* __restrict__ nt_emb, const float* __restrict__ rule_emb,
                            f16* __restrict__ xemb) {
  int bt = blockIdx.x;                 // b*256 + t
  int b = bt >> 8, t = bt & 255;
  int nti = nt[bt], pri = prev_r[bt], pai = par_r[bt];
  f16* dst = xemb + ((long)t * Bn + b) * 1536;
  for (int k = threadIdx.x; k < 1536; k += 256) {
    float v;
    if (k < 512)       v = nt_emb[(long)nti * 512 + k];
    else if (k < 1024) v = rule_emb[(long)pri * 512 + (k - 512)];
    else               v = rule_emb[(long)pai * 512 + (k - 1024)];
    dst[k] = (f16)v;
  }
}

// slot 0 of bufh (=zeros) and barrier flags must be MALL-visible (system stores),
// since the recurrence reads them with L2-bypassing loads.
__global__ void k_prep_state(f16* __restrict__ bufh, int* __restrict__ flags) {
  int idx = blockIdx.x * 256 + threadIdx.x;   // 96 blocks -> 24576
  if (idx < 16384) {
    __hip_atomic_store((unsigned int*)bufh + idx, 0u, __ATOMIC_RELAXED,
                       __HIP_MEMORY_SCOPE_SYSTEM);
  } else {
    __hip_atomic_store(flags + (idx - 16384), 0, __ATOMIC_RELAXED,
                       __HIP_MEMORY_SCOPE_SYSTEM);
  }
}

// ---------------------------------------------------------------------------
// Phase 1: sequential LSTM recurrence.
// 256 blocks x 512 threads (cooperative-launched for residency guarantee,
// but uses a custom MALL flag barrier -- grid.sync's L2 inval was the R1 stall).
// Block jt owns h-columns [jt*4, jt*4+4) x 4 gates = 16 gate-rows; its W-slice
// (114 KB) lives in LDS for the whole kernel. 8 waves split K=3584 8-ways.
// bufh layout: [slot][b][1024] f16, accessed ONLY via system-scope (MALL) ops.
// ---------------------------------------------------------------------------
struct GatesArgs {
  const f16* xemb; const f16* Wcomb; f16* bufh; const float* bcomb;
  const float* c0; const int* parent_t; int* flags;
};

__global__ void __launch_bounds__(512, 1) k_gates(GatesArgs a) {
  const int jt = blockIdx.x;
  const int tid = threadIdx.x;
  const int wave = tid >> 6;
  const int lane = tid & 63;
  const int l15 = lane & 15, quad = lane >> 4;

  extern __shared__ char smem[];
  f16 (*sW)[SW_PAD] = (f16(*)[SW_PAD])smem;          // 16 x 3592 f16 = 114,944 B
  float* sC    = (float*)(smem + 114944);            // [4][2][16][16] = 8,192 B
  float* sBias = (float*)(smem + 123136);            // 16 f
  float* c_lds = (float*)(smem + 123200);            // 128 f
  int*   spidx = (int*)(smem + 123712);              // 32 int
  // total 123,840 B

  // ---- preload W slice: packed row n = g*4+jj -> global gate-row g*1024+jt*4+jj
  for (int i = tid; i < 16 * 448; i += 512) {
    int n = i / 448, kk = (i % 448) * 8;
    int gr = (n >> 2) * Hn + jt * 4 + (n & 3);
    *(h8*)&sW[n][kk] = *(const h8*)(a.Wcomb + (long)gr * KT + kk);
  }
  if (tid < 16) sBias[tid] = a.bcomb[(tid >> 2) * Hn + jt * 4 + (tid & 3)];
  if (tid < 128) c_lds[tid] = a.c0[(tid >> 2) * Hn + jt * 4 + (tid & 3)];
  __syncthreads();

  for (int t = 0; t < Tn; ++t) {
    if (tid < 32) {
      int pt = a.parent_t[tid * Tn + t];
      spidx[tid] = (pt < t) ? pt + 1 : 0;
    }
    __syncthreads();  // sync1: spidx ready; also protects sC reuse across steps

    const int pidx0 = spidx[l15];
    const int pidx1 = spidx[16 + l15];
    const f16* xr = a.xemb + (long)t * Bn * 1536;
    const f16* ps0 = a.bufh + (((long)pidx0 * Bn + l15) << 10);
    const f16* ps1 = a.bufh + (((long)pidx1 * Bn + 16 + l15) << 10);
    const f16* hp0 = a.bufh + (((long)t * Bn + l15) << 10);
    const f16* hp1 = a.bufh + (((long)t * Bn + 16 + l15) << 10);

    f4 acc0 = (f4){0.f, 0.f, 0.f, 0.f}, acc1 = (f4){0.f, 0.f, 0.f, 0.f};

    for (int ks = 0; ks < 14; ++ks) {
      int kb = wave * 448 + ks * 32;     // chunk base (wave-uniform; 1536/2560 align)
      int k = kb + quad * 8;
      h8 a0, a1;
      if (kb < 1536) {                   // embeddings: normal (L2-cached) loads
        a0 = *(const h8*)(xr + (long)l15 * 1536 + k);
        a1 = *(const h8*)(xr + (long)(16 + l15) * 1536 + k);
      } else if (kb < INn) {             // parent state: MALL loads
        a0 = ld_sys16(ps0 + (k - 1536));
        a1 = ld_sys16(ps1 + (k - 1536));
      } else {                           // h_prev: MALL loads
        a0 = ld_sys16(hp0 + (k - INn));
        a1 = ld_sys16(hp1 + (k - INn));
      }
      h8 bf = *(const h8*)&sW[l15][k];
      acc0 = mfma_f16(a0, bf, acc0);
      acc1 = mfma_f16(a1, bf, acc1);
    }

    // two-stage K-reduction across 8 waves into 8 KB LDS
    float* myC0 = sC + (((wave & 3) * 2 + 0) * 16 + quad * 4) * 16 + l15;
    float* myC1 = sC + (((wave & 3) * 2 + 1) * 16 + quad * 4) * 16 + l15;
    if (wave < 4) {
#pragma unroll
      for (int r = 0; r < 4; ++r) { myC0[r * 16] = acc0[r]; myC1[r * 16] = acc1[r]; }
    }
    __syncthreads();  // sync2
    if (wave >= 4) {
#pragma unroll
      for (int r = 0; r < 4; ++r) { myC0[r * 16] += acc0[r]; myC1[r * 16] += acc1[r]; }
    }
    __syncthreads();  // sync3

    // fused cell: 128 threads = 32 batches x 4 h-cols
    if (tid < 128) {
      int b = tid >> 2, jj = tid & 3;
      int mt = b >> 4, row = b & 15;
      float g0 = 0.f, g1 = 0.f, g2 = 0.f, g3 = 0.f;
#pragma unroll
      for (int w = 0; w < 4; ++w) {
        const float* base = sC + ((w * 2 + mt) * 16 + row) * 16 + jj;
        g0 += base[0]; g1 += base[4]; g2 += base[8]; g3 += base[12];
      }
      g0 += sBias[jj]; g1 += sBias[4 + jj]; g2 += sBias[8 + jj]; g3 += sBias[12 + jj];
      float cp = c_lds[tid];
      float cn = sigm(g1) * cp + sigm(g0) * tanhf(g2);
      float hn = sigm(g3) * tanhf(cn);
      c_lds[tid] = cn;
      f16 hv = (f16)hn;
      __hip_atomic_store((unsigned short*)(a.bufh + (((long)(t + 1) * Bn + b) << 10)
                                           + jt * 4 + jj),
                         __builtin_bit_cast(unsigned short, hv),
                         __ATOMIC_RELAXED, __HIP_MEMORY_SCOPE_SYSTEM);
    }

    // ---- MALL flag barrier (no L2 writeback/invalidate) ----
    asm volatile("s_waitcnt vmcnt(0)" ::: "memory");  // drain own wave's h-stores
    __syncthreads();  // sync4: all storing waves drained
    if (tid == 0)
      __hip_atomic_store(&a.flags[blockIdx.x * 32], t + 1,
                         __ATOMIC_RELAXED, __HIP_MEMORY_SCOPE_SYSTEM);
    if (t < Tn - 1) {
      if (tid < 64) {
        bool ok = false;
        do {
          int f0 = __hip_atomic_load(&a.flags[(tid * 4 + 0) * 32], __ATOMIC_RELAXED, __HIP_MEMORY_SCOPE_SYSTEM);
          int f1 = __hip_atomic_load(&a.flags[(tid * 4 + 1) * 32], __ATOMIC_RELAXED, __HIP_MEMORY_SCOPE_SYSTEM);
          int f2 = __hip_atomic_load(&a.flags[(tid * 4 + 2) * 32], __ATOMIC_RELAXED, __HIP_MEMORY_SCOPE_SYSTEM);
          int f3 = __hip_atomic_load(&a.flags[(tid * 4 + 3) * 32], __ATOMIC_RELAXED, __HIP_MEMORY_SCOPE_SYSTEM);
          int tgt = t + 1;
          ok = (f0 >= tgt) && (f1 >= tgt) && (f2 >= tgt) && (f3 >= tgt);
        } while (!__all(ok));
      }
      __syncthreads();  // sync5: release all waves into step t+1
    }
  }
}

// ---------------------------------------------------------------------------
// Phase 2: bulk attention GEMMs (unchanged from R1 except bufh layout)
// ---------------------------------------------------------------------------
__global__ void k_qgemm(const f16* __restrict__ A, const f16* __restrict__ W,
                        f16* __restrict__ out, int a_mode) {
  int tid = threadIdx.x, lane = tid & 63, wave = tid >> 6;
  int l15 = lane & 15, quad = lane >> 4;
  int wm = wave & 1, wn = wave >> 1;
  int bm = blockIdx.y * 64 + wm * 32, bn = blockIdx.x * 64 + wn * 32;

  const f16* arow[2]; const f16* brow[2];
#pragma unroll
  for (int i = 0; i < 2; ++i) {
    int m = bm + i * 16 + l15;
    arow[i] = a_mode ? A + (((long)(m & 255) + 1) * Bn + (m >> 8)) * 1024
                     : A + (long)m * 1024;
  }
#pragma unroll
  for (int j = 0; j < 2; ++j) brow[j] = W + (long)(bn + j * 16 + l15) * 1024;

  f4 acc[2][2];
#pragma unroll
  for (int i = 0; i < 2; ++i)
#pragma unroll
    for (int j = 0; j < 2; ++j) acc[i][j] = (f4){0.f, 0.f, 0.f, 0.f};

  for (int ks = 0; ks < 32; ++ks) {
    int k = ks * 32 + quad * 8;
    h8 af[2] = {*(const h8*)(arow[0] + k), *(const h8*)(arow[1] + k)};
    h8 bf[2] = {*(const h8*)(brow[0] + k), *(const h8*)(brow[1] + k)};
#pragma unroll
    for (int i = 0; i < 2; ++i)
#pragma unroll
      for (int j = 0; j < 2; ++j) acc[i][j] = mfma_f16(af[i], bf[j], acc[i][j]);
  }
#pragma unroll
  for (int i = 0; i < 2; ++i)
#pragma unroll
    for (int j = 0; j < 2; ++j)
#pragma unroll
      for (int r = 0; r < 4; ++r) {
        int m = bm + i * 16 + quad * 4 + r;
        int n = bn + j * 16 + l15;
        out[(long)m * 1024 + n] = (f16)acc[i][j][r];
      }
}

__global__ void k_scores(const f16* __restrict__ Q, const f16* __restrict__ C16,
                         float* __restrict__ outp) {
  int tid = threadIdx.x, lane = tid & 63, wave = tid >> 6;
  int l15 = lane & 15, quad = lane >> 4;
  int wm = wave & 1, wn = wave >> 1;
  int b = blockIdx.z;
  int bm = blockIdx.y * 64 + wm * 32, bn = blockIdx.x * 64 + wn * 32;
  const f16* A = Q + (long)b * 256 * 1024;
  const f16* Bp = C16 + (long)b * 256 * 1024;
  const f16* arow[2]; const f16* brow[2];
#pragma unroll
  for (int i = 0; i < 2; ++i) arow[i] = A + (long)(bm + i * 16 + l15) * 1024;
#pragma unroll
  for (int j = 0; j < 2; ++j) brow[j] = Bp + (long)(bn + j * 16 + l15) * 1024;
  f4 acc[2][2];
#pragma unroll
  for (int i = 0; i < 2; ++i)
#pragma unroll
    for (int j = 0; j < 2; ++j) acc[i][j] = (f4){0.f, 0.f, 0.f, 0.f};
  for (int ks = 0; ks < 32; ++ks) {
    int k = ks * 32 + quad * 8;
    h8 af[2] = {*(const h8*)(arow[0] + k), *(const h8*)(arow[1] + k)};
    h8 bf[2] = {*(const h8*)(brow[0] + k), *(const h8*)(brow[1] + k)};
#pragma unroll
    for (int i = 0; i < 2; ++i)
#pragma unroll
      for (int j = 0; j < 2; ++j) acc[i][j] = mfma_f16(af[i], bf[j], acc[i][j]);
  }
#pragma unroll
  for (int i = 0; i < 2; ++i)
#pragma unroll
    for (int j = 0; j < 2; ++j)
#pragma unroll
      for (int r = 0; r < 4; ++r) {
        int m = bm + i * 16 + quad * 4 + r;
        int n = bn + j * 16 + l15;
        outp[((long)b * 256 + m) * 256 + n] = acc[i][j][r];
      }
}

__global__ void k_softmax(float* __restrict__ rows, const int* __restrict__ ctx_len,
                          f16* __restrict__ pout) {
  int tid = threadIdx.x;
  long base = (long)blockIdx.x * 256;
  int b = blockIdx.x >> 8;
  int len = ctx_len[b];
  float v = rows[base + tid];
  bool valid = tid < len;
  __shared__ float red[256];
  red[tid] = valid ? v : -3.0e38f;
  __syncthreads();
  for (int o = 128; o > 0; o >>= 1) {
    if (tid < o) red[tid] = fmaxf(red[tid], red[tid + o]);
    __syncthreads();
  }
  float m = red[0];
  __syncthreads();
  float e = valid ? __expf(v - m) : 0.f;
  red[tid] = e;
  __syncthreads();
  for (int o = 128; o > 0; o >>= 1) {
    if (tid < o) red[tid] += red[tid + o];
    __syncthreads();
  }
  float p = e / red[0];
  rows[base + tid] = p;
  if (pout) pout[base + tid] = (f16)p;
}

__global__ void k_cvec(const f16* __restrict__ P, const f16* __restrict__ CT,
                       f16* __restrict__ out) {
  int tid = threadIdx.x, lane = tid & 63, wave = tid >> 6;
  int l15 = lane & 15, quad = lane >> 4;
  int wm = wave & 1, wn = wave >> 1;
  int b = blockIdx.z;
  int bm = blockIdx.y * 64 + wm * 32, bn = blockIdx.x * 64 + wn * 32;
  const f16* A = P + (long)b * 256 * 256;
  const f16* Bp = CT + (long)b * 1024 * 256;
  const f16* arow[2]; const f16* brow[2];
#pragma unroll
  for (int i = 0; i < 2; ++i) arow[i] = A + (long)(bm + i * 16 + l15) * 256;
#pragma unroll
  for (int j = 0; j < 2; ++j) brow[j] = Bp + (long)(bn + j * 16 + l15) * 256;
  f4 acc[2][2];
#pragma unroll
  for (int i = 0; i < 2; ++i)
#pragma unroll
    for (int j = 0; j < 2; ++j) acc[i][j] = (f4){0.f, 0.f, 0.f, 0.f};
  for (int ks = 0; ks < 8; ++ks) {
    int k = ks * 32 + quad * 8;
    h8 af[2] = {*(const h8*)(arow[0] + k), *(const h8*)(arow[1] + k)};
    h8 bf[2] = {*(const h8*)(brow[0] + k), *(const h8*)(brow[1] + k)};
#pragma unroll
    for (int i = 0; i < 2; ++i)
#pragma unroll
      for (int j = 0; j < 2; ++j) acc[i][j] = mfma_f16(af[i], bf[j], acc[i][j]);
  }
#pragma unroll
  for (int i = 0; i < 2; ++i)
#pragma unroll
    for (int j = 0; j < 2; ++j)
#pragma unroll
      for (int r = 0; r < 4; ++r) {
        int m = bm + i * 16 + quad * 4 + r;
        int n = bn + j * 16 + l15;
        out[((long)b * 256 + m) * 1024 + n] = (f16)acc[i][j][r];
      }
}

__global__ void k_aout(const f16* __restrict__ CV, const f16* __restrict__ bufh,
                       const f16* __restrict__ W, float* __restrict__ outf,
                       f16* __restrict__ outh) {
  int tid = threadIdx.x, lane = tid & 63, wave = tid >> 6;
  int l15 = lane & 15, quad = lane >> 4;
  int wm = wave & 1, wn = wave >> 1;
  int bm = blockIdx.y * 64 + wm * 32, bn = blockIdx.x * 64 + wn * 32;
  const f16* arow1[2]; const f16* arow2[2]; const f16* brow[2];
#pragma unroll
  for (int i = 0; i < 2; ++i) {
    int m = bm + i * 16 + l15;
    arow1[i] = CV + (long)m * 1024;
    arow2[i] = bufh + (((long)(m & 255) + 1) * Bn + (m >> 8)) * 1024;
  }
#pragma unroll
  for (int j = 0; j < 2; ++j) brow[j] = W + (long)(bn + j * 16 + l15) * 2048;
  f4 acc[2][2];
#pragma unroll
  for (int i = 0; i < 2; ++i)
#pragma unroll
    for (int j = 0; j < 2; ++j) acc[i][j] = (f4){0.f, 0.f, 0.f, 0.f};
  for (int ks = 0; ks < 64; ++ks) {
    int k = ks * 32 + quad * 8;
    h8 af[2], bf[2];
    if (k < 1024) {
      af[0] = *(const h8*)(arow1[0] + k);
      af[1] = *(const h8*)(arow1[1] + k);
    } else {
      af[0] = *(const h8*)(arow2[0] + (k - 1024));
      af[1] = *(const h8*)(arow2[1] + (k - 1024));
    }
    bf[0] = *(const h8*)(brow[0] + k);
    bf[1] = *(const h8*)(brow[1] + k);
#pragma unroll
    for (int i = 0; i < 2; ++i)
#pragma unroll
      for (int j = 0; j < 2; ++j) acc[i][j] = mfma_f16(af[i], bf[j], acc[i][j]);
  }
#pragma unroll
  for (int i = 0; i < 2; ++i)
#pragma unroll
    for (int j = 0; j < 2; ++j)
#pragma unroll
      for (int r = 0; r < 4; ++r) {
        int m = bm + i * 16 + quad * 4 + r;
        int n = bn + j * 16 + l15;
        float v = tanhf(acc[i][j][r]);
        outf[(long)m * 1024 + n] = v;
        outh[(long)m * 1024 + n] = (f16)v;
      }
}

// ---------------------------------------------------------------------------
extern "C" void kernel_launch(void* const* d_in, const int* in_sizes, int n_in,
                              void* d_out, int out_size, void* d_ws, size_t ws_size,
                              hipStream_t stream) {
  const int*   nt        = (const int*)d_in[0];
  const int*   prev_r    = (const int*)d_in[1];
  const int*   par_r     = (const int*)d_in[2];
  const int*   parent_t  = (const int*)d_in[3];
  const float* context   = (const float*)d_in[4];
  const int*   ctx_len   = (const int*)d_in[5];
  const float* c0        = (const float*)d_in[7];   // h0 (d_in[6]) zeros == buf slot 0
  const float* nt_emb    = (const float*)d_in[8];
  const float* rule_emb  = (const float*)d_in[9];
  const float* W_ih      = (const float*)d_in[10];
  const float* W_hh      = (const float*)d_in[11];
  const float* b_ih      = (const float*)d_in[12];
  const float* b_hh      = (const float*)d_in[13];
  const float* Wa_in     = (const float*)d_in[14];
  const float* Wa_out    = (const float*)d_in[15];
  const float* Wc_in     = (const float*)d_in[16];
  // d_in[17] (Wc_out) unused: reference discards copy-attention's output proj.
  float* out = (float*)d_out;

  char* ws = (char*)d_ws;
  f16*   bufh  = (f16*)(ws);                       // [257][32][1024]   16,842,752 B
  f16*   xemb  = (f16*)(ws + 16842752L);           // [256][32][1536]   25,165,824
  f16*   Wcomb = (f16*)(ws + 42008576L);           // [4096][3584]      29,360,128
  f16*   Wain  = (f16*)(ws + 71368704L);           // [1024][1024]       2,097,152
  f16*   Wcin  = (f16*)(ws + 73465856L);           // [1024][1024]       2,097,152
  f16*   Waout = (f16*)(ws + 75563008L);           // [1024][2048]       4,194,304
  f16*   ctx16 = (f16*)(ws + 79757312L);           // [32][256][1024]   16,777,216
  f16*   ctxT  = (f16*)(ws + 96534528L);           // [32][1024][256]   16,777,216
  f16*   qbuf  = (f16*)(ws + 113311744L);          // [8192][1024]      16,777,216
  f16*   pbuf  = (f16*)(ws + 130088960L);          // [8192][256]        4,194,304
  f16*   cvec  = (f16*)(ws + 134283264L);          // [8192][1024]      16,777,216
  f16*   aout16= (f16*)(ws + 151060480L);          // [8192][1024]      16,777,216
  int*   flags = (int*)(ws + 167837696L);          // [256][32] int         32,768
  float* bcomb = (float*)(ws + 167968768L);        // [4096] fp32           16,384

  float* attn_out = out + 8388608;   // [B,T,S]
  float* copy_out = out + 10485760;  // [B,T,S]

  // -------- prep --------
  hipLaunchKernelGGL(k_prep_weights, dim3(73744), dim3(256), 0, stream,
                     W_ih, W_hh, Wa_in, Wc_in, Wa_out, b_ih, b_hh,
                     Wcomb, Wain, Wcin, Waout, bcomb);
  hipLaunchKernelGGL(k_prep_ctx, dim3(32768), dim3(256), 0, stream, context, ctx16, ctxT);
  hipLaunchKernelGGL(k_prep_xemb, dim3(8192), dim3(256), 0, stream,
                     nt, prev_r, par_r, nt_emb, rule_emb, xemb);
  hipLaunchKernelGGL(k_prep_state, dim3(96), dim3(256), 0, stream, bufh, flags);

  // -------- phase 1: sequential recurrence --------
  GatesArgs ga{xemb, Wcomb, bufh, bcomb, c0, parent_t, flags};
  void* gp[] = {&ga};
  hipLaunchCooperativeKernel((void*)k_gates, dim3(256), dim3(512), gp, 123840, stream);

  // -------- phase 2: bulk attention over all (b,t) --------
  hipLaunchKernelGGL(k_qgemm, dim3(16, 128), dim3(256), 0, stream, bufh, Wain, qbuf, 1);
  hipLaunchKernelGGL(k_scores, dim3(4, 4, 32), dim3(256), 0, stream, qbuf, ctx16, attn_out);
  hipLaunchKernelGGL(k_softmax, dim3(8192), dim3(256), 0, stream, attn_out, ctx_len, pbuf);
  hipLaunchKernelGGL(k_cvec, dim3(16, 4, 32), dim3(256), 0, stream, pbuf, ctxT, cvec);
  hipLaunchKernelGGL(k_aout, dim3(16, 128), dim3(256), 0, stream, cvec, bufh, Waout, out, aout16);
  hipLaunchKernelGGL(k_qgemm, dim3(16, 128), dim3(256), 0, stream, aout16, Wcin, qbuf, 0);
  hipLaunchKernelGGL(k_scores, dim3(4, 4, 32), dim3(256), 0, stream, qbuf, ctx16, copy_out);
  hipLaunchKernelGGL(k_softmax, dim3(8192), dim3(256), 0, stream, copy_out, ctx_len, (f16*)nullptr);
}

// Round 3
// 3007.449 us; speedup vs baseline: 2.8168x; 1.3748x over previous
//
#include <hip/hip_runtime.h>

typedef _Float16 f16;
typedef _Float16 h8 __attribute__((ext_vector_type(8)));
typedef float f4 __attribute__((ext_vector_type(4)));

#define Bn 32
#define Tn 256
#define Sn 256
#define Hn 1024
#define INn 2560          // 3*D + H
#define KT 3584           // INn + Hn (combined gates K)
#define SW_PAD 3592       // 3584 + 8 f16 pad
#define SLOT 32832        // bufh slot stride in f16: 32*1024 + 64 (128B guard pad)

__device__ __forceinline__ f4 mfma_f16(h8 a, h8 b, f4 c) {
  return __builtin_amdgcn_mfma_f32_16x16x32_f16(a, b, c, 0, 0, 0);
}
__device__ __forceinline__ float sigm(float x) { return 1.0f / (1.0f + __expf(-x)); }

// ---------------------------------------------------------------------------
// prep kernels
// ---------------------------------------------------------------------------
__global__ void k_prep_weights(const float* __restrict__ W_ih, const float* __restrict__ W_hh,
                               const float* __restrict__ Wa_in, const float* __restrict__ Wc_in,
                               const float* __restrict__ Wa_out, const float* __restrict__ b_ih,
                               const float* __restrict__ b_hh,
                               f16* __restrict__ Wcomb, f16* __restrict__ Wain,
                               f16* __restrict__ Wcin, f16* __restrict__ Waout,
                               float* __restrict__ bcomb) {
  long idx = (long)blockIdx.x * 256 + threadIdx.x;
  if (idx < 14680064L) {  // Wcomb[4096][3584] = [W_ih | W_hh] rows
    int n = (int)(idx / KT), k = (int)(idx % KT);
    float v = (k < INn) ? W_ih[(long)n * INn + k] : W_hh[(long)n * Hn + (k - INn)];
    Wcomb[idx] = (f16)v;
    return;
  }
  idx -= 14680064L;
  if (idx < 1048576) { Wain[idx] = (f16)Wa_in[idx]; return; }
  idx -= 1048576;
  if (idx < 1048576) { Wcin[idx] = (f16)Wc_in[idx]; return; }
  idx -= 1048576;
  if (idx < 2097152) { Waout[idx] = (f16)Wa_out[idx]; return; }
  idx -= 2097152;
  if (idx < 4096) bcomb[idx] = b_ih[idx] + b_hh[idx];
}

__global__ void k_prep_ctx(const float* __restrict__ context,
                           f16* __restrict__ ctx16, f16* __restrict__ ctxT) {
  int idx = blockIdx.x * 256 + threadIdx.x;       // 8388608
  int b = idx >> 18;
  int rem = idx & 262143;
  int s = rem >> 10, k = rem & 1023;
  float v = context[idx];
  ctx16[idx] = (f16)v;
  ctxT[((long)b << 18) + ((long)k << 8) + s] = (f16)v;  // [b][k][s]
}

// xemb layout [t][b][1536]: per-step slice is one contiguous 96 KB blob
__global__ void k_prep_xemb(const int* __restrict__ nt, const int* __restrict__ prev_r,
                            const int* __restrict__ par_r,
                            const float* __restrict__ nt_emb, const float* __restrict__ rule_emb,
                            f16* __restrict__ xemb) {
  int bt = blockIdx.x;                 // b*256 + t
  int b = bt >> 8, t = bt & 255;
  int nti = nt[bt], pri = prev_r[bt], pai = par_r[bt];
  f16* dst = xemb + ((long)t * Bn + b) * 1536;
  for (int k = threadIdx.x; k < 1536; k += 256) {
    float v;
    if (k < 512)       v = nt_emb[(long)nti * 512 + k];
    else if (k < 1024) v = rule_emb[(long)pri * 512 + (k - 512)];
    else               v = rule_emb[(long)pai * 512 + (k - 1024)];
    dst[k] = (f16)v;
  }
}

// slot 0 of bufh (=zeros, MALL-visible) and barrier flags
__global__ void k_prep_state(f16* __restrict__ bufh, int* __restrict__ flags) {
  int idx = blockIdx.x * 256 + threadIdx.x;   // 96 blocks -> 24576
  if (idx < 16384) {
    __hip_atomic_store((unsigned int*)bufh + idx, 0u, __ATOMIC_RELAXED,
                       __HIP_MEMORY_SCOPE_SYSTEM);
  } else {
    __hip_atomic_store(flags + (idx - 16384), 0, __ATOMIC_RELAXED,
                       __HIP_MEMORY_SCOPE_SYSTEM);
  }
}

// ---------------------------------------------------------------------------
// Phase 1: sequential LSTM recurrence. 256 blocks x 512 threads (cooperative).
// Block jt owns h-cols [jt*4,jt*4+4) x 4 gates; W slice (114KB) LDS-resident.
// bufh: WRITTEN system-scope (straight to MALL, no L2 pollution), READ with
// plain L2-cached loads (safe: slot lines enter L2 only post-barrier, written
// once; dispatch-acquire invalidated L2 at kernel start). L2 multicasts the
// h broadcast per-XCD: MALL serves 8x128KB/step instead of 256x (R2's stall).
// Per step: phase A = xemb K[0,1536) overlapped with wave0 flag-poll; then
// phase B = pstate/h_prev K[1536,3584).
// ---------------------------------------------------------------------------
struct GatesArgs {
  const f16* xemb; const f16* Wcomb; f16* bufh; const float* bcomb;
  const float* c0; const int* parent_t; int* flags;
};

__global__ void __launch_bounds__(512, 1) k_gates(GatesArgs a) {
  const int jt = blockIdx.x;
  const int tid = threadIdx.x;
  const int wave = tid >> 6;
  const int lane = tid & 63;
  const int l15 = lane & 15, quad = lane >> 4;

  extern __shared__ char smem[];
  f16 (*sW)[SW_PAD] = (f16(*)[SW_PAD])smem;          // 16 x 3592 f16 = 114,944 B
  float* sC    = (float*)(smem + 114944);            // [4][2][16][16] = 8,192 B
  float* sBias = (float*)(smem + 123136);            // 16 f
  float* c_lds = (float*)(smem + 123200);            // 128 f
  f16*   sH    = (f16*)(smem + 123712);              // 128 f16 = 256 B
  int*   spidx = (int*)(smem + 123968);              // 32 int
  // total 124,096 B

  // ---- preload W slice: packed row n = g*4+jj -> global gate-row g*1024+jt*4+jj
  for (int i = tid; i < 16 * 448; i += 512) {
    int n = i / 448, kk = (i % 448) * 8;
    int gr = (n >> 2) * Hn + jt * 4 + (n & 3);
    *(h8*)&sW[n][kk] = *(const h8*)(a.Wcomb + (long)gr * KT + kk);
  }
  if (tid < 16) sBias[tid] = a.bcomb[(tid >> 2) * Hn + jt * 4 + (tid & 3)];
  if (tid < 128) c_lds[tid] = a.c0[(tid >> 2) * Hn + jt * 4 + (tid & 3)];
  __syncthreads();

  for (int t = 0; t < Tn; ++t) {
    if (tid < 32) {
      int pt = a.parent_t[tid * Tn + t];
      spidx[tid] = (pt < t) ? pt + 1 : 0;
    }

    // ---- phase A: xemb K [0,1536), no dependence on step t-1's h ----
    const f16* xr0 = a.xemb + ((long)t * Bn + l15) * 1536;
    const f16* xr1 = xr0 + 16 * 1536;
    f4 acc0 = (f4){0.f, 0.f, 0.f, 0.f}, acc1 = (f4){0.f, 0.f, 0.f, 0.f};
#pragma unroll
    for (int ks = 0; ks < 6; ++ks) {
      int k = wave * 192 + ks * 32 + quad * 8;
      h8 a0 = *(const h8*)(xr0 + k);
      h8 a1 = *(const h8*)(xr1 + k);
      h8 bf = *(const h8*)&sW[l15][k];
      acc0 = mfma_f16(a0, bf, acc0);
      acc1 = mfma_f16(a1, bf, acc1);
    }

    // ---- barrier wait (overlapped with phase A on waves 1-7) ----
    if (t > 0 && wave == 0) {
      bool ok = false;
      do {
        int f0 = __hip_atomic_load(&a.flags[(lane * 4 + 0) * 32], __ATOMIC_RELAXED, __HIP_MEMORY_SCOPE_SYSTEM);
        int f1 = __hip_atomic_load(&a.flags[(lane * 4 + 1) * 32], __ATOMIC_RELAXED, __HIP_MEMORY_SCOPE_SYSTEM);
        int f2 = __hip_atomic_load(&a.flags[(lane * 4 + 2) * 32], __ATOMIC_RELAXED, __HIP_MEMORY_SCOPE_SYSTEM);
        int f3 = __hip_atomic_load(&a.flags[(lane * 4 + 3) * 32], __ATOMIC_RELAXED, __HIP_MEMORY_SCOPE_SYSTEM);
        ok = (f0 >= t) && (f1 >= t) && (f2 >= t) && (f3 >= t);
      } while (!__all(ok));
    }
    __syncthreads();  // S1: releases phase B; spidx visible; orders loads after poll

    // ---- phase B: pstate K [1536,2560) (waves 0-3), h_prev [2560,3584) (4-7) ----
    const f16* b0;
    const f16* b1;
    int koff;
    if (wave < 4) {
      int pidx0 = spidx[l15], pidx1 = spidx[16 + l15];
      b0 = a.bufh + (long)pidx0 * SLOT + (long)l15 * 1024;
      b1 = a.bufh + (long)pidx1 * SLOT + (long)(16 + l15) * 1024;
      koff = 1536;
    } else {
      b0 = a.bufh + (long)t * SLOT + (long)l15 * 1024;
      b1 = a.bufh + (long)t * SLOT + (long)(16 + l15) * 1024;
      koff = 2560;
    }
#pragma unroll
    for (int ks = 0; ks < 8; ++ks) {
      int k = 1536 + wave * 256 + ks * 32 + quad * 8;
      h8 a0 = *(const h8*)(b0 + (k - koff));
      h8 a1 = *(const h8*)(b1 + (k - koff));
      h8 bf = *(const h8*)&sW[l15][k];
      acc0 = mfma_f16(a0, bf, acc0);
      acc1 = mfma_f16(a1, bf, acc1);
    }

    // ---- two-stage K-reduction across 8 waves into LDS ----
    float* myC0 = sC + (((wave & 3) * 2 + 0) * 16 + quad * 4) * 16 + l15;
    float* myC1 = sC + (((wave & 3) * 2 + 1) * 16 + quad * 4) * 16 + l15;
    if (wave < 4) {
#pragma unroll
      for (int r = 0; r < 4; ++r) { myC0[r * 16] = acc0[r]; myC1[r * 16] = acc1[r]; }
    }
    __syncthreads();  // S2
    if (wave >= 4) {
#pragma unroll
      for (int r = 0; r < 4; ++r) { myC0[r * 16] += acc0[r]; myC1[r * 16] += acc1[r]; }
    }
    __syncthreads();  // S3

    // ---- fused cell: 128 threads = 32 batches x 4 h-cols; h -> LDS ----
    if (tid < 128) {
      int b = tid >> 2, jj = tid & 3;
      int mt = b >> 4, row = b & 15;
      float g0 = 0.f, g1 = 0.f, g2 = 0.f, g3 = 0.f;
#pragma unroll
      for (int w = 0; w < 4; ++w) {
        const float* base = sC + ((w * 2 + mt) * 16 + row) * 16 + jj;
        g0 += base[0]; g1 += base[4]; g2 += base[8]; g3 += base[12];
      }
      g0 += sBias[jj]; g1 += sBias[4 + jj]; g2 += sBias[8 + jj]; g3 += sBias[12 + jj];
      float cp = c_lds[tid];
      float cn = sigm(g1) * cp + sigm(g0) * tanhf(g2);
      float hn = sigm(g3) * tanhf(cn);
      c_lds[tid] = cn;
      sH[tid] = (f16)hn;   // sH[b*4+jj]
    }
    __syncthreads();  // S4: sH ready; also guards sC reuse next step

    // ---- coalesced h publish: 32 x 8B system stores (straight to MALL) ----
    if (tid < 32) {
      unsigned long long v = *(const unsigned long long*)(sH + tid * 4);
      __hip_atomic_store((unsigned long long*)(a.bufh + (long)(t + 1) * SLOT
                                               + (long)tid * 1024 + jt * 4),
                         v, __ATOMIC_RELAXED, __HIP_MEMORY_SCOPE_SYSTEM);
    }
    asm volatile("s_waitcnt vmcnt(0)" ::: "memory");  // drain h before flag
    if (tid == 0)
      __hip_atomic_store(&a.flags[blockIdx.x * 32], t + 1,
                         __ATOMIC_RELAXED, __HIP_MEMORY_SCOPE_SYSTEM);
  }
}

// ---------------------------------------------------------------------------
// Phase 2: bulk attention GEMMs
// ---------------------------------------------------------------------------
__global__ void k_qgemm(const f16* __restrict__ A, const f16* __restrict__ W,
                        f16* __restrict__ out, int a_mode) {
  int tid = threadIdx.x, lane = tid & 63, wave = tid >> 6;
  int l15 = lane & 15, quad = lane >> 4;
  int wm = wave & 1, wn = wave >> 1;
  int bm = blockIdx.y * 64 + wm * 32, bn = blockIdx.x * 64 + wn * 32;

  const f16* arow[2]; const f16* brow[2];
#pragma unroll
  for (int i = 0; i < 2; ++i) {
    int m = bm + i * 16 + l15;
    arow[i] = a_mode ? A + (long)((m & 255) + 1) * SLOT + (long)(m >> 8) * 1024
                     : A + (long)m * 1024;
  }
#pragma unroll
  for (int j = 0; j < 2; ++j) brow[j] = W + (long)(bn + j * 16 + l15) * 1024;

  f4 acc[2][2];
#pragma unroll
  for (int i = 0; i < 2; ++i)
#pragma unroll
    for (int j = 0; j < 2; ++j) acc[i][j] = (f4){0.f, 0.f, 0.f, 0.f};

  for (int ks = 0; ks < 32; ++ks) {
    int k = ks * 32 + quad * 8;
    h8 af[2] = {*(const h8*)(arow[0] + k), *(const h8*)(arow[1] + k)};
    h8 bf[2] = {*(const h8*)(brow[0] + k), *(const h8*)(brow[1] + k)};
#pragma unroll
    for (int i = 0; i < 2; ++i)
#pragma unroll
      for (int j = 0; j < 2; ++j) acc[i][j] = mfma_f16(af[i], bf[j], acc[i][j]);
  }
#pragma unroll
  for (int i = 0; i < 2; ++i)
#pragma unroll
    for (int j = 0; j < 2; ++j)
#pragma unroll
      for (int r = 0; r < 4; ++r) {
        int m = bm + i * 16 + quad * 4 + r;
        int n = bn + j * 16 + l15;
        out[(long)m * 1024 + n] = (f16)acc[i][j][r];
      }
}

__global__ void k_scores(const f16* __restrict__ Q, const f16* __restrict__ C16,
                         float* __restrict__ outp) {
  int tid = threadIdx.x, lane = tid & 63, wave = tid >> 6;
  int l15 = lane & 15, quad = lane >> 4;
  int wm = wave & 1, wn = wave >> 1;
  int b = blockIdx.z;
  int bm = blockIdx.y * 64 + wm * 32, bn = blockIdx.x * 64 + wn * 32;
  const f16* A = Q + (long)b * 256 * 1024;
  const f16* Bp = C16 + (long)b * 256 * 1024;
  const f16* arow[2]; const f16* brow[2];
#pragma unroll
  for (int i = 0; i < 2; ++i) arow[i] = A + (long)(bm + i * 16 + l15) * 1024;
#pragma unroll
  for (int j = 0; j < 2; ++j) brow[j] = Bp + (long)(bn + j * 16 + l15) * 1024;
  f4 acc[2][2];
#pragma unroll
  for (int i = 0; i < 2; ++i)
#pragma unroll
    for (int j = 0; j < 2; ++j) acc[i][j] = (f4){0.f, 0.f, 0.f, 0.f};
  for (int ks = 0; ks < 32; ++ks) {
    int k = ks * 32 + quad * 8;
    h8 af[2] = {*(const h8*)(arow[0] + k), *(const h8*)(arow[1] + k)};
    h8 bf[2] = {*(const h8*)(brow[0] + k), *(const h8*)(brow[1] + k)};
#pragma unroll
    for (int i = 0; i < 2; ++i)
#pragma unroll
      for (int j = 0; j < 2; ++j) acc[i][j] = mfma_f16(af[i], bf[j], acc[i][j]);
  }
#pragma unroll
  for (int i = 0; i < 2; ++i)
#pragma unroll
    for (int j = 0; j < 2; ++j)
#pragma unroll
      for (int r = 0; r < 4; ++r) {
        int m = bm + i * 16 + quad * 4 + r;
        int n = bn + j * 16 + l15;
        outp[((long)b * 256 + m) * 256 + n] = acc[i][j][r];
      }
}

__global__ void k_softmax(float* __restrict__ rows, const int* __restrict__ ctx_len,
                          f16* __restrict__ pout) {
  int tid = threadIdx.x;
  long base = (long)blockIdx.x * 256;
  int b = blockIdx.x >> 8;
  int len = ctx_len[b];
  float v = rows[base + tid];
  bool valid = tid < len;
  __shared__ float red[256];
  red[tid] = valid ? v : -3.0e38f;
  __syncthreads();
  for (int o = 128; o > 0; o >>= 1) {
    if (tid < o) red[tid] = fmaxf(red[tid], red[tid + o]);
    __syncthreads();
  }
  float m = red[0];
  __syncthreads();
  float e = valid ? __expf(v - m) : 0.f;
  red[tid] = e;
  __syncthreads();
  for (int o = 128; o > 0; o >>= 1) {
    if (tid < o) red[tid] += red[tid + o];
    __syncthreads();
  }
  float p = e / red[0];
  rows[base + tid] = p;
  if (pout) pout[base + tid] = (f16)p;
}

__global__ void k_cvec(const f16* __restrict__ P, const f16* __restrict__ CT,
                       f16* __restrict__ out) {
  int tid = threadIdx.x, lane = tid & 63, wave = tid >> 6;
  int l15 = lane & 15, quad = lane >> 4;
  int wm = wave & 1, wn = wave >> 1;
  int b = blockIdx.z;
  int bm = blockIdx.y * 64 + wm * 32, bn = blockIdx.x * 64 + wn * 32;
  const f16* A = P + (long)b * 256 * 256;
  const f16* Bp = CT + (long)b * 1024 * 256;
  const f16* arow[2]; const f16* brow[2];
#pragma unroll
  for (int i = 0; i < 2; ++i) arow[i] = A + (long)(bm + i * 16 + l15) * 256;
#pragma unroll
  for (int j = 0; j < 2; ++j) brow[j] = Bp + (long)(bn + j * 16 + l15) * 256;
  f4 acc[2][2];
#pragma unroll
  for (int i = 0; i < 2; ++i)
#pragma unroll
    for (int j = 0; j < 2; ++j) acc[i][j] = (f4){0.f, 0.f, 0.f, 0.f};
  for (int ks = 0; ks < 8; ++ks) {
    int k = ks * 32 + quad * 8;
    h8 af[2] = {*(const h8*)(arow[0] + k), *(const h8*)(arow[1] + k)};
    h8 bf[2] = {*(const h8*)(brow[0] + k), *(const h8*)(brow[1] + k)};
#pragma unroll
    for (int i = 0; i < 2; ++i)
#pragma unroll
      for (int j = 0; j < 2; ++j) acc[i][j] = mfma_f16(af[i], bf[j], acc[i][j]);
  }
#pragma unroll
  for (int i = 0; i < 2; ++i)
#pragma unroll
    for (int j = 0; j < 2; ++j)
#pragma unroll
      for (int r = 0; r < 4; ++r) {
        int m = bm + i * 16 + quad * 4 + r;
        int n = bn + j * 16 + l15;
        out[((long)b * 256 + m) * 1024 + n] = (f16)acc[i][j][r];
      }
}

__global__ void k_aout(const f16* __restrict__ CV, const f16* __restrict__ bufh,
                       const f16* __restrict__ W, float* __restrict__ outf,
                       f16* __restrict__ outh) {
  int tid = threadIdx.x, lane = tid & 63, wave = tid >> 6;
  int l15 = lane & 15, quad = lane >> 4;
  int wm = wave & 1, wn = wave >> 1;
  int bm = blockIdx.y * 64 + wm * 32, bn = blockIdx.x * 64 + wn * 32;
  const f16* arow1[2]; const f16* arow2[2]; const f16* brow[2];
#pragma unroll
  for (int i = 0; i < 2; ++i) {
    int m = bm + i * 16 + l15;
    arow1[i] = CV + (long)m * 1024;
    arow2[i] = bufh + (long)((m & 255) + 1) * SLOT + (long)(m >> 8) * 1024;
  }
#pragma unroll
  for (int j = 0; j < 2; ++j) brow[j] = W + (long)(bn + j * 16 + l15) * 2048;
  f4 acc[2][2];
#pragma unroll
  for (int i = 0; i < 2; ++i)
#pragma unroll
    for (int j = 0; j < 2; ++j) acc[i][j] = (f4){0.f, 0.f, 0.f, 0.f};
  for (int ks = 0; ks < 64; ++ks) {
    int k = ks * 32 + quad * 8;
    h8 af[2], bf[2];
    if (k < 1024) {
      af[0] = *(const h8*)(arow1[0] + k);
      af[1] = *(const h8*)(arow1[1] + k);
    } else {
      af[0] = *(const h8*)(arow2[0] + (k - 1024));
      af[1] = *(const h8*)(arow2[1] + (k - 1024));
    }
    bf[0] = *(const h8*)(brow[0] + k);
    bf[1] = *(const h8*)(brow[1] + k);
#pragma unroll
    for (int i = 0; i < 2; ++i)
#pragma unroll
      for (int j = 0; j < 2; ++j) acc[i][j] = mfma_f16(af[i], bf[j], acc[i][j]);
  }
#pragma unroll
  for (int i = 0; i < 2; ++i)
#pragma unroll
    for (int j = 0; j < 2; ++j)
#pragma unroll
      for (int r = 0; r < 4; ++r) {
        int m = bm + i * 16 + quad * 4 + r;
        int n = bn + j * 16 + l15;
        float v = tanhf(acc[i][j][r]);
        outf[(long)m * 1024 + n] = v;
        outh[(long)m * 1024 + n] = (f16)v;
      }
}

// ---------------------------------------------------------------------------
extern "C" void kernel_launch(void* const* d_in, const int* in_sizes, int n_in,
                              void* d_out, int out_size, void* d_ws, size_t ws_size,
                              hipStream_t stream) {
  const int*   nt        = (const int*)d_in[0];
  const int*   prev_r    = (const int*)d_in[1];
  const int*   par_r     = (const int*)d_in[2];
  const int*   parent_t  = (const int*)d_in[3];
  const float* context   = (const float*)d_in[4];
  const int*   ctx_len   = (const int*)d_in[5];
  const float* c0        = (const float*)d_in[7];   // h0 (d_in[6]) zeros == buf slot 0
  const float* nt_emb    = (const float*)d_in[8];
  const float* rule_emb  = (const float*)d_in[9];
  const float* W_ih      = (const float*)d_in[10];
  const float* W_hh      = (const float*)d_in[11];
  const float* b_ih      = (const float*)d_in[12];
  const float* b_hh      = (const float*)d_in[13];
  const float* Wa_in     = (const float*)d_in[14];
  const float* Wa_out    = (const float*)d_in[15];
  const float* Wc_in     = (const float*)d_in[16];
  // d_in[17] (Wc_out) unused: reference discards copy-attention's output proj.
  float* out = (float*)d_out;

  char* ws = (char*)d_ws;
  f16*   bufh  = (f16*)(ws);                       // [257][32832] f16  16,875,648 B
  f16*   xemb  = (f16*)(ws + 16875648L);           // [256][32][1536]   25,165,824
  f16*   Wcomb = (f16*)(ws + 42041472L);           // [4096][3584]      29,360,128
  f16*   Wain  = (f16*)(ws + 71401600L);           // [1024][1024]       2,097,152
  f16*   Wcin  = (f16*)(ws + 73498752L);           // [1024][1024]       2,097,152
  f16*   Waout = (f16*)(ws + 75595904L);           // [1024][2048]       4,194,304
  f16*   ctx16 = (f16*)(ws + 79790208L);           // [32][256][1024]   16,777,216
  f16*   ctxT  = (f16*)(ws + 96567424L);           // [32][1024][256]   16,777,216
  f16*   qbuf  = (f16*)(ws + 113344640L);          // [8192][1024]      16,777,216
  f16*   pbuf  = (f16*)(ws + 130121856L);          // [8192][256]        4,194,304
  f16*   cvec  = (f16*)(ws + 134316160L);          // [8192][1024]      16,777,216
  f16*   aout16= (f16*)(ws + 151093376L);          // [8192][1024]      16,777,216
  int*   flags = (int*)(ws + 167870592L);          // [256][32] int         32,768
  float* bcomb = (float*)(ws + 167903360L);        // [4096] fp32           16,384

  float* attn_out = out + 8388608;   // [B,T,S]
  float* copy_out = out + 10485760;  // [B,T,S]

  // -------- prep --------
  hipLaunchKernelGGL(k_prep_weights, dim3(73744), dim3(256), 0, stream,
                     W_ih, W_hh, Wa_in, Wc_in, Wa_out, b_ih, b_hh,
                     Wcomb, Wain, Wcin, Waout, bcomb);
  hipLaunchKernelGGL(k_prep_ctx, dim3(32768), dim3(256), 0, stream, context, ctx16, ctxT);
  hipLaunchKernelGGL(k_prep_xemb, dim3(8192), dim3(256), 0, stream,
                     nt, prev_r, par_r, nt_emb, rule_emb, xemb);
  hipLaunchKernelGGL(k_prep_state, dim3(96), dim3(256), 0, stream, bufh, flags);

  // -------- phase 1: sequential recurrence --------
  GatesArgs ga{xemb, Wcomb, bufh, bcomb, c0, parent_t, flags};
  void* gp[] = {&ga};
  hipLaunchCooperativeKernel((void*)k_gates, dim3(256), dim3(512), gp, 124096, stream);

  // -------- phase 2: bulk attention over all (b,t) --------
  hipLaunchKernelGGL(k_qgemm, dim3(16, 128), dim3(256), 0, stream, bufh, Wain, qbuf, 1);
  hipLaunchKernelGGL(k_scores, dim3(4, 4, 32), dim3(256), 0, stream, qbuf, ctx16, attn_out);
  hipLaunchKernelGGL(k_softmax, dim3(8192), dim3(256), 0, stream, attn_out, ctx_len, pbuf);
  hipLaunchKernelGGL(k_cvec, dim3(16, 4, 32), dim3(256), 0, stream, pbuf, ctxT, cvec);
  hipLaunchKernelGGL(k_aout, dim3(16, 128), dim3(256), 0, stream, cvec, bufh, Waout, out, aout16);
  hipLaunchKernelGGL(k_qgemm, dim3(16, 128), dim3(256), 0, stream, aout16, Wcin, qbuf, 0);
  hipLaunchKernelGGL(k_scores, dim3(4, 4, 32), dim3(256), 0, stream, qbuf, ctx16, copy_out);
  hipLaunchKernelGGL(k_softmax, dim3(8192), dim3(256), 0, stream, copy_out, ctx_len, (f16*)nullptr);
}

// Round 4
// 2931.723 us; speedup vs baseline: 2.8896x; 1.0258x over previous
//
#include <hip/hip_runtime.h>

typedef _Float16 f16;
typedef _Float16 h8 __attribute__((ext_vector_type(8)));
typedef float f4 __attribute__((ext_vector_type(4)));

#define Bn 32
#define Tn 256
#define Sn 256
#define Hn 1024
#define INn 2560          // 3*D + H
#define KT 3584           // INn + Hn (combined gates K)
#define SW_PAD 3592       // 3584 + 8 f16 pad
#define SLOT 32832        // bufh slot stride in f16: 32*1024 + 64 (128B guard pad)
#define SC_PAD 17         // sC row stride in floats (16 + 1: breaks 4-way quad conflict)

__device__ __forceinline__ f4 mfma_f16(h8 a, h8 b, f4 c) {
  return __builtin_amdgcn_mfma_f32_16x16x32_f16(a, b, c, 0, 0, 0);
}
__device__ __forceinline__ float sigm(float x) { return 1.0f / (1.0f + __expf(-x)); }

// ---------------------------------------------------------------------------
// prep kernels
// ---------------------------------------------------------------------------
__global__ void k_prep_weights(const float* __restrict__ W_ih, const float* __restrict__ W_hh,
                               const float* __restrict__ Wa_in, const float* __restrict__ Wc_in,
                               const float* __restrict__ Wa_out, const float* __restrict__ b_ih,
                               const float* __restrict__ b_hh,
                               f16* __restrict__ Wcomb, f16* __restrict__ Wain,
                               f16* __restrict__ Wcin, f16* __restrict__ Waout,
                               float* __restrict__ bcomb) {
  long idx = (long)blockIdx.x * 256 + threadIdx.x;
  if (idx < 14680064L) {  // Wcomb[4096][3584] = [W_ih | W_hh] rows
    int n = (int)(idx / KT), k = (int)(idx % KT);
    float v = (k < INn) ? W_ih[(long)n * INn + k] : W_hh[(long)n * Hn + (k - INn)];
    Wcomb[idx] = (f16)v;
    return;
  }
  idx -= 14680064L;
  if (idx < 1048576) { Wain[idx] = (f16)Wa_in[idx]; return; }
  idx -= 1048576;
  if (idx < 1048576) { Wcin[idx] = (f16)Wc_in[idx]; return; }
  idx -= 1048576;
  if (idx < 2097152) { Waout[idx] = (f16)Wa_out[idx]; return; }
  idx -= 2097152;
  if (idx < 4096) bcomb[idx] = b_ih[idx] + b_hh[idx];
}

__global__ void k_prep_ctx(const float* __restrict__ context,
                           f16* __restrict__ ctx16, f16* __restrict__ ctxT) {
  int idx = blockIdx.x * 256 + threadIdx.x;       // 8388608
  int b = idx >> 18;
  int rem = idx & 262143;
  int s = rem >> 10, k = rem & 1023;
  float v = context[idx];
  ctx16[idx] = (f16)v;
  ctxT[((long)b << 18) + ((long)k << 8) + s] = (f16)v;  // [b][k][s]
}

// xemb layout [t][b][1536]: per-step slice is one contiguous 96 KB blob
__global__ void k_prep_xemb(const int* __restrict__ nt, const int* __restrict__ prev_r,
                            const int* __restrict__ par_r,
                            const float* __restrict__ nt_emb, const float* __restrict__ rule_emb,
                            f16* __restrict__ xemb) {
  int bt = blockIdx.x;                 // b*256 + t
  int b = bt >> 8, t = bt & 255;
  int nti = nt[bt], pri = prev_r[bt], pai = par_r[bt];
  f16* dst = xemb + ((long)t * Bn + b) * 1536;
  for (int k = threadIdx.x; k < 1536; k += 256) {
    float v;
    if (k < 512)       v = nt_emb[(long)nti * 512 + k];
    else if (k < 1024) v = rule_emb[(long)pri * 512 + (k - 512)];
    else               v = rule_emb[(long)pai * 512 + (k - 1024)];
    dst[k] = (f16)v;
  }
}

// slot 0 of bufh (=zeros, MALL-visible), worker flags [256], epoch copies [8 x 64B]
__global__ void k_prep_state(f16* __restrict__ bufh, int* __restrict__ flags) {
  int idx = blockIdx.x * 256 + threadIdx.x;   // 96 blocks -> 24576
  if (idx < 16384) {
    __hip_atomic_store((unsigned int*)bufh + idx, 0u, __ATOMIC_RELAXED,
                       __HIP_MEMORY_SCOPE_SYSTEM);
  } else if (idx < 16384 + 640) {
    __hip_atomic_store(flags + (idx - 16384), 0, __ATOMIC_RELAXED,
                       __HIP_MEMORY_SCOPE_SYSTEM);
  }
}

// ---------------------------------------------------------------------------
// Phase 1: sequential LSTM recurrence. 256 blocks x 512 threads (cooperative).
// Block jt owns h-cols [jt*4,jt*4+4) x 4 gates; W slice (114KB) LDS-resident.
// bufh: written system-scope (straight to MALL), read with plain L2-cached
// loads (slot lines enter L2 only post-barrier; written once).
// Barrier (R4): single-aggregator epoch. Workers publish packed flags[jt]
// (16 lines total); block 0 polls those and publishes an epoch word (x8
// replicas, 64B apart); workers poll ONE line. Kills R3's 4MB/round MALL
// poll storm (256 blocks x 256 lines) that congested every latency in the
// publish->detect->load chain.
// ---------------------------------------------------------------------------
struct GatesArgs {
  const f16* xemb; const f16* Wcomb; f16* bufh; const float* bcomb;
  const float* c0; const int* parent_t; int* flags;
};

__global__ void __launch_bounds__(512, 1) k_gates(GatesArgs a) {
  const int jt = blockIdx.x;
  const int tid = threadIdx.x;
  const int wave = tid >> 6;
  const int lane = tid & 63;
  const int l15 = lane & 15, quad = lane >> 4;

  extern __shared__ char smem[];
  f16 (*sW)[SW_PAD] = (f16(*)[SW_PAD])smem;          // 16 x 3592 f16 = 114,944 B
  float* sC    = (float*)(smem + 114944);            // 8 x 16 x 17 f = 8,704 B
  float* sBias = (float*)(smem + 123648);            // 16 f
  float* c_lds = (float*)(smem + 123712);            // 128 f
  f16*   sH    = (f16*)(smem + 124224);              // 128 f16 = 256 B
  int*   spidx = (int*)(smem + 124480);              // 32 int
  // total 124,608 B

  // ---- preload W slice: packed row n = g*4+jj -> global gate-row g*1024+jt*4+jj
  for (int i = tid; i < 16 * 448; i += 512) {
    int n = i / 448, kk = (i % 448) * 8;
    int gr = (n >> 2) * Hn + jt * 4 + (n & 3);
    *(h8*)&sW[n][kk] = *(const h8*)(a.Wcomb + (long)gr * KT + kk);
  }
  if (tid < 16) sBias[tid] = a.bcomb[(tid >> 2) * Hn + jt * 4 + (tid & 3)];
  if (tid < 128) c_lds[tid] = a.c0[(tid >> 2) * Hn + jt * 4 + (tid & 3)];
  __syncthreads();

  for (int t = 0; t < Tn; ++t) {
    if (tid < 32) {
      int pt = a.parent_t[tid * Tn + t];
      spidx[tid] = (pt < t) ? pt + 1 : 0;
    }

    // ---- phase A: xemb K [0,1536), no dependence on step t-1's h ----
    const f16* xr0 = a.xemb + ((long)t * Bn + l15) * 1536;
    const f16* xr1 = xr0 + 16 * 1536;
    f4 acc0 = (f4){0.f, 0.f, 0.f, 0.f}, acc1 = (f4){0.f, 0.f, 0.f, 0.f};
#pragma unroll
    for (int ks = 0; ks < 6; ++ks) {
      int k = wave * 192 + ks * 32 + quad * 8;
      h8 a0 = *(const h8*)(xr0 + k);
      h8 a1 = *(const h8*)(xr1 + k);
      h8 bf = *(const h8*)&sW[l15][k];
      acc0 = mfma_f16(a0, bf, acc0);
      acc1 = mfma_f16(a1, bf, acc1);
    }

    // ---- barrier wait (overlapped with phase A on waves 1-7) ----
    if (t > 0 && wave == 0) {
      if (jt == 0) {
        // aggregator: poll 256 packed flags (16 lines/round)
        bool ok = false;
        do {
          int f0 = __hip_atomic_load(&a.flags[lane],       __ATOMIC_RELAXED, __HIP_MEMORY_SCOPE_SYSTEM);
          int f1 = __hip_atomic_load(&a.flags[64 + lane],  __ATOMIC_RELAXED, __HIP_MEMORY_SCOPE_SYSTEM);
          int f2 = __hip_atomic_load(&a.flags[128 + lane], __ATOMIC_RELAXED, __HIP_MEMORY_SCOPE_SYSTEM);
          int f3 = __hip_atomic_load(&a.flags[192 + lane], __ATOMIC_RELAXED, __HIP_MEMORY_SCOPE_SYSTEM);
          ok = (f0 >= t) && (f1 >= t) && (f2 >= t) && (f3 >= t);
        } while (!__all(ok));
        if (lane < 8)   // publish epoch x8 replicas (64B apart)
          __hip_atomic_store(&a.flags[512 + lane * 16], t,
                             __ATOMIC_RELAXED, __HIP_MEMORY_SCOPE_SYSTEM);
      } else {
        // worker: poll one epoch replica (single 64B line, wave-uniform)
        const int ei = 512 + ((jt & 7) << 4);
        int e;
        do {
          e = __hip_atomic_load(&a.flags[ei], __ATOMIC_RELAXED, __HIP_MEMORY_SCOPE_SYSTEM);
        } while (e < t);
      }
    }
    __syncthreads();  // S1: releases phase B; spidx visible; orders loads after poll

    // ---- phase B: pstate K [1536,2560) (waves 0-3), h_prev [2560,3584) (4-7) ----
    const f16* b0;
    const f16* b1;
    int koff;
    if (wave < 4) {
      int pidx0 = spidx[l15], pidx1 = spidx[16 + l15];
      b0 = a.bufh + (long)pidx0 * SLOT + (long)l15 * 1024;
      b1 = a.bufh + (long)pidx1 * SLOT + (long)(16 + l15) * 1024;
      koff = 1536;
    } else {
      b0 = a.bufh + (long)t * SLOT + (long)l15 * 1024;
      b1 = a.bufh + (long)t * SLOT + (long)(16 + l15) * 1024;
      koff = 2560;
    }
#pragma unroll
    for (int ks = 0; ks < 8; ++ks) {
      int k = 1536 + wave * 256 + ks * 32 + quad * 8;
      h8 a0 = *(const h8*)(b0 + (k - koff));
      h8 a1 = *(const h8*)(b1 + (k - koff));
      h8 bf = *(const h8*)&sW[l15][k];
      acc0 = mfma_f16(a0, bf, acc0);
      acc1 = mfma_f16(a1, bf, acc1);
    }

    // ---- two-stage K-reduction across 8 waves into LDS (pad-17 rows) ----
    float* myC0 = sC + (((wave & 3) * 2 + 0) * 16 + quad * 4) * SC_PAD + l15;
    float* myC1 = sC + (((wave & 3) * 2 + 1) * 16 + quad * 4) * SC_PAD + l15;
    if (wave < 4) {
#pragma unroll
      for (int r = 0; r < 4; ++r) { myC0[r * SC_PAD] = acc0[r]; myC1[r * SC_PAD] = acc1[r]; }
    }
    __syncthreads();  // S2
    if (wave >= 4) {
#pragma unroll
      for (int r = 0; r < 4; ++r) { myC0[r * SC_PAD] += acc0[r]; myC1[r * SC_PAD] += acc1[r]; }
    }
    __syncthreads();  // S3

    // ---- fused cell: 128 threads = 32 batches x 4 h-cols; h -> LDS ----
    if (tid < 128) {
      int b = tid >> 2, jj = tid & 3;
      int mt = b >> 4, row = b & 15;
      float g0 = 0.f, g1 = 0.f, g2 = 0.f, g3 = 0.f;
#pragma unroll
      for (int w = 0; w < 4; ++w) {
        const float* base = sC + ((w * 2 + mt) * 16 + row) * SC_PAD + jj;
        g0 += base[0]; g1 += base[4]; g2 += base[8]; g3 += base[12];
      }
      g0 += sBias[jj]; g1 += sBias[4 + jj]; g2 += sBias[8 + jj]; g3 += sBias[12 + jj];
      float cp = c_lds[tid];
      float cn = sigm(g1) * cp + sigm(g0) * tanhf(g2);
      float hn = sigm(g3) * tanhf(cn);
      c_lds[tid] = cn;
      sH[tid] = (f16)hn;   // sH[b*4+jj]
    }
    __syncthreads();  // S4: sH ready; also guards sC reuse next step

    // ---- coalesced h publish: 32 x 8B system stores (straight to MALL) ----
    if (tid < 32) {
      unsigned long long v = *(const unsigned long long*)(sH + tid * 4);
      __hip_atomic_store((unsigned long long*)(a.bufh + (long)(t + 1) * SLOT
                                               + (long)tid * 1024 + jt * 4),
                         v, __ATOMIC_RELAXED, __HIP_MEMORY_SCOPE_SYSTEM);
    }
    asm volatile("s_waitcnt vmcnt(0)" ::: "memory");  // drain h before flag
    if (tid == 0)
      __hip_atomic_store(&a.flags[jt], t + 1,
                         __ATOMIC_RELAXED, __HIP_MEMORY_SCOPE_SYSTEM);
  }
}

// ---------------------------------------------------------------------------
// Phase 2: bulk attention GEMMs
// ---------------------------------------------------------------------------
__global__ void k_qgemm(const f16* __restrict__ A, const f16* __restrict__ W,
                        f16* __restrict__ out, int a_mode) {
  int tid = threadIdx.x, lane = tid & 63, wave = tid >> 6;
  int l15 = lane & 15, quad = lane >> 4;
  int wm = wave & 1, wn = wave >> 1;
  int bm = blockIdx.y * 64 + wm * 32, bn = blockIdx.x * 64 + wn * 32;

  const f16* arow[2]; const f16* brow[2];
#pragma unroll
  for (int i = 0; i < 2; ++i) {
    int m = bm + i * 16 + l15;
    arow[i] = a_mode ? A + (long)((m & 255) + 1) * SLOT + (long)(m >> 8) * 1024
                     : A + (long)m * 1024;
  }
#pragma unroll
  for (int j = 0; j < 2; ++j) brow[j] = W + (long)(bn + j * 16 + l15) * 1024;

  f4 acc[2][2];
#pragma unroll
  for (int i = 0; i < 2; ++i)
#pragma unroll
    for (int j = 0; j < 2; ++j) acc[i][j] = (f4){0.f, 0.f, 0.f, 0.f};

  for (int ks = 0; ks < 32; ++ks) {
    int k = ks * 32 + quad * 8;
    h8 af[2] = {*(const h8*)(arow[0] + k), *(const h8*)(arow[1] + k)};
    h8 bf[2] = {*(const h8*)(brow[0] + k), *(const h8*)(brow[1] + k)};
#pragma unroll
    for (int i = 0; i < 2; ++i)
#pragma unroll
      for (int j = 0; j < 2; ++j) acc[i][j] = mfma_f16(af[i], bf[j], acc[i][j]);
  }
#pragma unroll
  for (int i = 0; i < 2; ++i)
#pragma unroll
    for (int j = 0; j < 2; ++j)
#pragma unroll
      for (int r = 0; r < 4; ++r) {
        int m = bm + i * 16 + quad * 4 + r;
        int n = bn + j * 16 + l15;
        out[(long)m * 1024 + n] = (f16)acc[i][j][r];
      }
}

__global__ void k_scores(const f16* __restrict__ Q, const f16* __restrict__ C16,
                         float* __restrict__ outp) {
  int tid = threadIdx.x, lane = tid & 63, wave = tid >> 6;
  int l15 = lane & 15, quad = lane >> 4;
  int wm = wave & 1, wn = wave >> 1;
  int b = blockIdx.z;
  int bm = blockIdx.y * 64 + wm * 32, bn = blockIdx.x * 64 + wn * 32;
  const f16* A = Q + (long)b * 256 * 1024;
  const f16* Bp = C16 + (long)b * 256 * 1024;
  const f16* arow[2]; const f16* brow[2];
#pragma unroll
  for (int i = 0; i < 2; ++i) arow[i] = A + (long)(bm + i * 16 + l15) * 1024;
#pragma unroll
  for (int j = 0; j < 2; ++j) brow[j] = Bp + (long)(bn + j * 16 + l15) * 1024;
  f4 acc[2][2];
#pragma unroll
  for (int i = 0; i < 2; ++i)
#pragma unroll
    for (int j = 0; j < 2; ++j) acc[i][j] = (f4){0.f, 0.f, 0.f, 0.f};
  for (int ks = 0; ks < 32; ++ks) {
    int k = ks * 32 + quad * 8;
    h8 af[2] = {*(const h8*)(arow[0] + k), *(const h8*)(arow[1] + k)};
    h8 bf[2] = {*(const h8*)(brow[0] + k), *(const h8*)(brow[1] + k)};
#pragma unroll
    for (int i = 0; i < 2; ++i)
#pragma unroll
      for (int j = 0; j < 2; ++j) acc[i][j] = mfma_f16(af[i], bf[j], acc[i][j]);
  }
#pragma unroll
  for (int i = 0; i < 2; ++i)
#pragma unroll
    for (int j = 0; j < 2; ++j)
#pragma unroll
      for (int r = 0; r < 4; ++r) {
        int m = bm + i * 16 + quad * 4 + r;
        int n = bn + j * 16 + l15;
        outp[((long)b * 256 + m) * 256 + n] = acc[i][j][r];
      }
}

__global__ void k_softmax(float* __restrict__ rows, const int* __restrict__ ctx_len,
                          f16* __restrict__ pout) {
  int tid = threadIdx.x;
  long base = (long)blockIdx.x * 256;
  int b = blockIdx.x >> 8;
  int len = ctx_len[b];
  float v = rows[base + tid];
  bool valid = tid < len;
  __shared__ float red[256];
  red[tid] = valid ? v : -3.0e38f;
  __syncthreads();
  for (int o = 128; o > 0; o >>= 1) {
    if (tid < o) red[tid] = fmaxf(red[tid], red[tid + o]);
    __syncthreads();
  }
  float m = red[0];
  __syncthreads();
  float e = valid ? __expf(v - m) : 0.f;
  red[tid] = e;
  __syncthreads();
  for (int o = 128; o > 0; o >>= 1) {
    if (tid < o) red[tid] += red[tid + o];
    __syncthreads();
  }
  float p = e / red[0];
  rows[base + tid] = p;
  if (pout) pout[base + tid] = (f16)p;
}

__global__ void k_cvec(const f16* __restrict__ P, const f16* __restrict__ CT,
                       f16* __restrict__ out) {
  int tid = threadIdx.x, lane = tid & 63, wave = tid >> 6;
  int l15 = lane & 15, quad = lane >> 4;
  int wm = wave & 1, wn = wave >> 1;
  int b = blockIdx.z;
  int bm = blockIdx.y * 64 + wm * 32, bn = blockIdx.x * 64 + wn * 32;
  const f16* A = P + (long)b * 256 * 256;
  const f16* Bp = CT + (long)b * 1024 * 256;
  const f16* arow[2]; const f16* brow[2];
#pragma unroll
  for (int i = 0; i < 2; ++i) arow[i] = A + (long)(bm + i * 16 + l15) * 256;
#pragma unroll
  for (int j = 0; j < 2; ++j) brow[j] = Bp + (long)(bn + j * 16 + l15) * 256;
  f4 acc[2][2];
#pragma unroll
  for (int i = 0; i < 2; ++i)
#pragma unroll
    for (int j = 0; j < 2; ++j) acc[i][j] = (f4){0.f, 0.f, 0.f, 0.f};
  for (int ks = 0; ks < 8; ++ks) {
    int k = ks * 32 + quad * 8;
    h8 af[2] = {*(const h8*)(arow[0] + k), *(const h8*)(arow[1] + k)};
    h8 bf[2] = {*(const h8*)(brow[0] + k), *(const h8*)(brow[1] + k)};
#pragma unroll
    for (int i = 0; i < 2; ++i)
#pragma unroll
      for (int j = 0; j < 2; ++j) acc[i][j] = mfma_f16(af[i], bf[j], acc[i][j]);
  }
#pragma unroll
  for (int i = 0; i < 2; ++i)
#pragma unroll
    for (int j = 0; j < 2; ++j)
#pragma unroll
      for (int r = 0; r < 4; ++r) {
        int m = bm + i * 16 + quad * 4 + r;
        int n = bn + j * 16 + l15;
        out[((long)b * 256 + m) * 1024 + n] = (f16)acc[i][j][r];
      }
}

__global__ void k_aout(const f16* __restrict__ CV, const f16* __restrict__ bufh,
                       const f16* __restrict__ W, float* __restrict__ outf,
                       f16* __restrict__ outh) {
  int tid = threadIdx.x, lane = tid & 63, wave = tid >> 6;
  int l15 = lane & 15, quad = lane >> 4;
  int wm = wave & 1, wn = wave >> 1;
  int bm = blockIdx.y * 64 + wm * 32, bn = blockIdx.x * 64 + wn * 32;
  const f16* arow1[2]; const f16* arow2[2]; const f16* brow[2];
#pragma unroll
  for (int i = 0; i < 2; ++i) {
    int m = bm + i * 16 + l15;
    arow1[i] = CV + (long)m * 1024;
    arow2[i] = bufh + (long)((m & 255) + 1) * SLOT + (long)(m >> 8) * 1024;
  }
#pragma unroll
  for (int j = 0; j < 2; ++j) brow[j] = W + (long)(bn + j * 16 + l15) * 2048;
  f4 acc[2][2];
#pragma unroll
  for (int i = 0; i < 2; ++i)
#pragma unroll
    for (int j = 0; j < 2; ++j) acc[i][j] = (f4){0.f, 0.f, 0.f, 0.f};
  for (int ks = 0; ks < 64; ++ks) {
    int k = ks * 32 + quad * 8;
    h8 af[2], bf[2];
    if (k < 1024) {
      af[0] = *(const h8*)(arow1[0] + k);
      af[1] = *(const h8*)(arow1[1] + k);
    } else {
      af[0] = *(const h8*)(arow2[0] + (k - 1024));
      af[1] = *(const h8*)(arow2[1] + (k - 1024));
    }
    bf[0] = *(const h8*)(brow[0] + k);
    bf[1] = *(const h8*)(brow[1] + k);
#pragma unroll
    for (int i = 0; i < 2; ++i)
#pragma unroll
      for (int j = 0; j < 2; ++j) acc[i][j] = mfma_f16(af[i], bf[j], acc[i][j]);
  }
#pragma unroll
  for (int i = 0; i < 2; ++i)
#pragma unroll
    for (int j = 0; j < 2; ++j)
#pragma unroll
      for (int r = 0; r < 4; ++r) {
        int m = bm + i * 16 + quad * 4 + r;
        int n = bn + j * 16 + l15;
        float v = tanhf(acc[i][j][r]);
        outf[(long)m * 1024 + n] = v;
        outh[(long)m * 1024 + n] = (f16)v;
      }
}

// ---------------------------------------------------------------------------
extern "C" void kernel_launch(void* const* d_in, const int* in_sizes, int n_in,
                              void* d_out, int out_size, void* d_ws, size_t ws_size,
                              hipStream_t stream) {
  const int*   nt        = (const int*)d_in[0];
  const int*   prev_r    = (const int*)d_in[1];
  const int*   par_r     = (const int*)d_in[2];
  const int*   parent_t  = (const int*)d_in[3];
  const float* context   = (const float*)d_in[4];
  const int*   ctx_len   = (const int*)d_in[5];
  const float* c0        = (const float*)d_in[7];   // h0 (d_in[6]) zeros == buf slot 0
  const float* nt_emb    = (const float*)d_in[8];
  const float* rule_emb  = (const float*)d_in[9];
  const float* W_ih      = (const float*)d_in[10];
  const float* W_hh      = (const float*)d_in[11];
  const float* b_ih      = (const float*)d_in[12];
  const float* b_hh      = (const float*)d_in[13];
  const float* Wa_in     = (const float*)d_in[14];
  const float* Wa_out    = (const float*)d_in[15];
  const float* Wc_in     = (const float*)d_in[16];
  // d_in[17] (Wc_out) unused: reference discards copy-attention's output proj.
  float* out = (float*)d_out;

  char* ws = (char*)d_ws;
  f16*   bufh  = (f16*)(ws);                       // [257][32832] f16  16,875,648 B
  f16*   xemb  = (f16*)(ws + 16875648L);           // [256][32][1536]   25,165,824
  f16*   Wcomb = (f16*)(ws + 42041472L);           // [4096][3584]      29,360,128
  f16*   Wain  = (f16*)(ws + 71401600L);           // [1024][1024]       2,097,152
  f16*   Wcin  = (f16*)(ws + 73498752L);           // [1024][1024]       2,097,152
  f16*   Waout = (f16*)(ws + 75595904L);           // [1024][2048]       4,194,304
  f16*   ctx16 = (f16*)(ws + 79790208L);           // [32][256][1024]   16,777,216
  f16*   ctxT  = (f16*)(ws + 96567424L);           // [32][1024][256]   16,777,216
  f16*   qbuf  = (f16*)(ws + 113344640L);          // [8192][1024]      16,777,216
  f16*   pbuf  = (f16*)(ws + 130121856L);          // [8192][256]        4,194,304
  f16*   cvec  = (f16*)(ws + 134316160L);          // [8192][1024]      16,777,216
  f16*   aout16= (f16*)(ws + 151093376L);          // [8192][1024]      16,777,216
  int*   flags = (int*)(ws + 167870592L);          // [640] int (flags+epoch)
  float* bcomb = (float*)(ws + 167903360L);        // [4096] fp32           16,384

  float* attn_out = out + 8388608;   // [B,T,S]
  float* copy_out = out + 10485760;  // [B,T,S]

  // -------- prep --------
  hipLaunchKernelGGL(k_prep_weights, dim3(73744), dim3(256), 0, stream,
                     W_ih, W_hh, Wa_in, Wc_in, Wa_out, b_ih, b_hh,
                     Wcomb, Wain, Wcin, Waout, bcomb);
  hipLaunchKernelGGL(k_prep_ctx, dim3(32768), dim3(256), 0, stream, context, ctx16, ctxT);
  hipLaunchKernelGGL(k_prep_xemb, dim3(8192), dim3(256), 0, stream,
                     nt, prev_r, par_r, nt_emb, rule_emb, xemb);
  hipLaunchKernelGGL(k_prep_state, dim3(96), dim3(256), 0, stream, bufh, flags);

  // -------- phase 1: sequential recurrence --------
  GatesArgs ga{xemb, Wcomb, bufh, bcomb, c0, parent_t, flags};
  void* gp[] = {&ga};
  hipLaunchCooperativeKernel((void*)k_gates, dim3(256), dim3(512), gp, 124608, stream);

  // -------- phase 2: bulk attention over all (b,t) --------
  hipLaunchKernelGGL(k_qgemm, dim3(16, 128), dim3(256), 0, stream, bufh, Wain, qbuf, 1);
  hipLaunchKernelGGL(k_scores, dim3(4, 4, 32), dim3(256), 0, stream, qbuf, ctx16, attn_out);
  hipLaunchKernelGGL(k_softmax, dim3(8192), dim3(256), 0, stream, attn_out, ctx_len, pbuf);
  hipLaunchKernelGGL(k_cvec, dim3(16, 4, 32), dim3(256), 0, stream, pbuf, ctxT, cvec);
  hipLaunchKernelGGL(k_aout, dim3(16, 128), dim3(256), 0, stream, cvec, bufh, Waout, out, aout16);
  hipLaunchKernelGGL(k_qgemm, dim3(16, 128), dim3(256), 0, stream, aout16, Wcin, qbuf, 0);
  hipLaunchKernelGGL(k_scores, dim3(4, 4, 32), dim3(256), 0, stream, qbuf, ctx16, copy_out);
  hipLaunchKernelGGL(k_softmax, dim3(8192), dim3(256), 0, stream, copy_out, ctx_len, (f16*)nullptr);
}